// Round 1
// baseline (3389.995 us; speedup 1.0000x reference)
//
#include <hip/hip_runtime.h>
#include <hip/hip_bf16.h>
#include <math.h>

// ---------------------------------------------------------------------------
// MoE block: router + grouped-expert SwiGLU + shared SwiGLU MLP.
// Round 1: correctness-first bf16 MFMA implementation (m97-class structure).
// ---------------------------------------------------------------------------

typedef __bf16 bf16_t;
typedef __bf16 bf16x8 __attribute__((ext_vector_type(8)));
typedef float  f32x4  __attribute__((ext_vector_type(4)));

constexpr int NTOK = 8192;          // B*S
constexpr int D    = 2048;
constexpr int E    = 32;
constexpr int I    = 1024;
constexpr int TK   = 8;             // TOP_K
constexpr int NK   = NTOK * TK;     // 65536 slots
constexpr int BM   = 128;
constexpr int BK   = 64;
constexpr int MAX_TILES = E + NK / BM;   // 544 worst-case row tiles
constexpr float RSCALE = 2.5f;

// ------------------------------- utilities --------------------------------

__global__ __launch_bounds__(64) void k_zero_meta(int* counts, int* cursors, int* ntl) {
    int t = threadIdx.x;
    if (t < E) { counts[t] = 0; cursors[t] = 0; }
    if (t == 0) *ntl = 0;
}

__global__ __launch_bounds__(64) void k_sentinel(float* out) {
    if (threadIdx.x == 0) out[0] = 12345.0f;   // signals ws_size too small
}

// f32 -> bf16, 8 elems/thread
__global__ __launch_bounds__(256) void k_convert_x(const float* __restrict__ src,
                                                   bf16_t* __restrict__ dst, int n8) {
    int i = blockIdx.x * 256 + threadIdx.x;
    if (i >= n8) return;
    const float4* s = (const float4*)src;
    float4 a = s[(size_t)i * 2], b = s[(size_t)i * 2 + 1];
    bf16_t t[8] = {(bf16_t)a.x, (bf16_t)a.y, (bf16_t)a.z, (bf16_t)a.w,
                   (bf16_t)b.x, (bf16_t)b.y, (bf16_t)b.z, (bf16_t)b.w};
    *(uint4*)(dst + (size_t)i * 8) = *(const uint4*)t;
}

// batched transpose+convert: src [b][R][C] f32 -> dst [b][C][R] bf16
__global__ __launch_bounds__(256) void k_transpose(const float* __restrict__ src,
                                                   bf16_t* __restrict__ dst,
                                                   int R, int C) {
    __shared__ float t[32][33];
    int b = blockIdx.z;
    size_t mat = (size_t)R * C;
    const float* s = src + (size_t)b * mat;
    bf16_t* d = dst + (size_t)b * mat;
    int c0 = blockIdx.x * 32, r0 = blockIdx.y * 32;
    int tx = threadIdx.x, ty = threadIdx.y;    // 32 x 8
#pragma unroll
    for (int yy = 0; yy < 4; yy++)
        t[ty + yy * 8][tx] = s[(size_t)(r0 + ty + yy * 8) * C + c0 + tx];
    __syncthreads();
#pragma unroll
    for (int yy = 0; yy < 4; yy++)
        d[(size_t)(c0 + ty + yy * 8) * R + r0 + tx] = (bf16_t)t[tx][ty + yy * 8];
}

// ------------------------------- router -----------------------------------
// one block per token; exact replication of the reference top-k semantics
// (stable descending, lower index wins ties).

__global__ __launch_bounds__(256) void k_router(const float* __restrict__ x,
                                                const float* __restrict__ gw,
                                                const float* __restrict__ eb,
                                                float* __restrict__ out_idx,
                                                float* __restrict__ out_scores,
                                                float* __restrict__ topk_w,
                                                int* __restrict__ tok_expert,
                                                int* __restrict__ counts) {
    int t = blockIdx.x;
    int tid = threadIdx.x;
    int e = tid & 31, part = tid >> 5;         // 8 parts x 256 d each
    const float* xr = x + (size_t)t * D;
    float partial = 0.f;
    int d0 = part * 256;
    for (int d = d0; d < d0 + 256; d++)
        partial += xr[d] * gw[(size_t)d * E + e];

    __shared__ float red[8][32];
    __shared__ float sc[32], sfr[32];
    red[part][e] = partial;
    __syncthreads();
    if (tid < 32) {
        float l = 0.f;
#pragma unroll
        for (int p = 0; p < 8; p++) l += red[p][tid];
        float s = 1.f / (1.f + expf(-l));
        sc[tid] = s;
        sfr[tid] = s + eb[tid];
        out_scores[(size_t)t * E + tid] = s;
    }
    __syncthreads();
    if (tid == 0) {
        // per-group top-2 sum (8 groups of 4)
        float gs[8];
#pragma unroll
        for (int g = 0; g < 8; g++) {
            float m1 = -1e30f, m2 = -1e30f;
#pragma unroll
            for (int i = 0; i < 4; i++) {
                float v = sfr[g * 4 + i];
                if (v > m1) { m2 = m1; m1 = v; } else if (v > m2) m2 = v;
            }
            gs[g] = m1 + m2;
        }
        // top-4 groups (ties -> lower index)
        bool gsel[8] = {false, false, false, false, false, false, false, false};
        for (int it = 0; it < 4; it++) {
            int bi = -1; float bv = -1e30f;
            for (int g = 0; g < 8; g++)
                if (!gsel[g] && gs[g] > bv) { bv = gs[g]; bi = g; }
            gsel[bi] = true;
        }
        float masked[32];
        for (int i = 0; i < 32; i++) masked[i] = gsel[i >> 2] ? sfr[i] : -1e30f;
        // top-8 experts (stable descending)
        int idx[TK]; float w[TK]; float wsum = 0.f;
        for (int k = 0; k < TK; k++) {
            int bi = 0; float bv = -1e30f;
            for (int i = 0; i < 32; i++)
                if (masked[i] > bv) { bv = masked[i]; bi = i; }
            masked[bi] = -1e30f;
            idx[k] = bi; w[k] = sc[bi]; wsum += w[k];
        }
        float inv = RSCALE / (wsum + 1e-20f);
        for (int k = 0; k < TK; k++) {
            out_idx[(size_t)t * TK + k] = (float)idx[k];
            topk_w[(size_t)t * TK + k] = w[k] * inv;
            tok_expert[(size_t)t * TK + k] = idx[k];
            atomicAdd(&counts[idx[k]], 1);
        }
    }
}

__global__ __launch_bounds__(64) void k_offsets(const int* __restrict__ counts,
                                                int* __restrict__ offs,
                                                int4* __restrict__ ttbl,
                                                int* __restrict__ ntl) {
    if (threadIdx.x != 0) return;
    int off = 0, nt = 0;
    for (int e = 0; e < E; e++) {
        offs[e] = off;
        int c = counts[e];
        for (int r = 0; r < c; r += BM) {
            ttbl[nt] = make_int4(off + r, min(BM, c - r), e, 0);
            nt++;
        }
        off += c;
    }
    offs[E] = off;
    *ntl = nt;
}

__global__ __launch_bounds__(256) void k_scatter(const int* __restrict__ tok_expert,
                                                 const float* __restrict__ topk_w,
                                                 const int* __restrict__ offs,
                                                 int* __restrict__ cursors,
                                                 int* __restrict__ slot_token,
                                                 float* __restrict__ slot_w) {
    int i = blockIdx.x * 256 + threadIdx.x;
    if (i >= NK) return;
    int e = tok_expert[i];
    int pos = offs[e] + atomicAdd(&cursors[e], 1);
    slot_token[pos] = i >> 3;   // TK = 8
    slot_w[pos] = topk_w[i];
}

// ------------------------------- GEMM 1 -----------------------------------
// inter[slot][ct*64+j] = silu(g) * u;  g = X[tok] . Wg_col, u = X[tok] . Wu_col
// A: x_bf16 [*, D] gathered by slot_token.  B: transposed weights [col][k].
// tile: 128 slots x 64 inter-cols; 4 waves, each 32 rows x 64 cols x {G,U}.

template <bool EXPERT>
__global__ __launch_bounds__(256) void k_gemm1(const bf16_t* __restrict__ Xb,
                                               const bf16_t* __restrict__ BgBase,
                                               const bf16_t* __restrict__ BuBase,
                                               size_t estride,
                                               const int* __restrict__ slot_token,
                                               const int4* __restrict__ ttbl,
                                               const int* __restrict__ ntl,
                                               bf16_t* __restrict__ inter) {
    int base_slot, rows, e;
    if (EXPERT) {
        if ((int)blockIdx.x >= *ntl) return;
        int4 tt = ttbl[blockIdx.x];
        base_slot = tt.x; rows = tt.y; e = tt.z;
    } else {
        base_slot = blockIdx.x * BM; rows = BM; e = 0;
    }
    int ct = blockIdx.y;
    const bf16_t* Bg = BgBase + (size_t)e * estride + (size_t)ct * 64 * D;
    const bf16_t* Bu = BuBase + (size_t)e * estride + (size_t)ct * 64 * D;

    __shared__ bf16_t As[BM][BK + 8];     // +8 pad: row stride 144B (2-way banks)
    __shared__ bf16_t Bs[BM][BK + 8];     // rows 0..63 gate cols, 64..127 up cols

    int tid = threadIdx.x, lane = tid & 63, wave = tid >> 6;
    f32x4 accG[2][4] = {};
    f32x4 accU[2][4] = {};

    for (int k0 = 0; k0 < D; k0 += BK) {
        // stage A (gathered rows, zero-pad invalid)
#pragma unroll
        for (int i = 0; i < 4; i++) {
            int c = tid + i * 256;
            int r = c >> 3, cc = (c & 7) * 8;
            uint4 v = make_uint4(0, 0, 0, 0);
            if (r < rows) {
                int tok = EXPERT ? slot_token[base_slot + r] : (base_slot + r);
                v = *(const uint4*)(Xb + (size_t)tok * D + k0 + cc);
            }
            *(uint4*)(&As[r][cc]) = v;
        }
        // stage B (gate rows then up rows)
#pragma unroll
        for (int i = 0; i < 4; i++) {
            int c = tid + i * 256;
            int r = c >> 3, cc = (c & 7) * 8;
            const bf16_t* srcp = (r < 64) ? (Bg + (size_t)r * D) : (Bu + (size_t)(r - 64) * D);
            *(uint4*)(&Bs[r][cc]) = *(const uint4*)(srcp + k0 + cc);
        }
        __syncthreads();
        int rA = wave * 32 + (lane & 15);
        int kg = (lane >> 4) * 8;
#pragma unroll
        for (int kk = 0; kk < BK; kk += 32) {
            bf16x8 a[2], bg[4], bu[4];
#pragma unroll
            for (int m = 0; m < 2; m++)
                a[m] = *(const bf16x8*)(&As[rA + m * 16][kk + kg]);
#pragma unroll
            for (int n = 0; n < 4; n++) {
                bg[n] = *(const bf16x8*)(&Bs[n * 16 + (lane & 15)][kk + kg]);
                bu[n] = *(const bf16x8*)(&Bs[64 + n * 16 + (lane & 15)][kk + kg]);
            }
#pragma unroll
            for (int m = 0; m < 2; m++)
#pragma unroll
                for (int n = 0; n < 4; n++) {
                    accG[m][n] = __builtin_amdgcn_mfma_f32_16x16x32_bf16(a[m], bg[n], accG[m][n], 0, 0, 0);
                    accU[m][n] = __builtin_amdgcn_mfma_f32_16x16x32_bf16(a[m], bu[n], accU[m][n], 0, 0, 0);
                }
        }
        __syncthreads();
    }
    // epilogue: D[row][col], col = lane&15, row = (lane>>4)*4 + j  (m89 layout)
#pragma unroll
    for (int m = 0; m < 2; m++) {
#pragma unroll
        for (int j = 0; j < 4; j++) {
            int r = wave * 32 + m * 16 + (lane >> 4) * 4 + j;
            if (r < rows) {
                size_t slot = (size_t)base_slot + r;
#pragma unroll
                for (int n = 0; n < 4; n++) {
                    float g = accG[m][n][j], u = accU[m][n][j];
                    float sv = g / (1.f + __expf(-g)) * u;
                    int col = ct * 64 + n * 16 + (lane & 15);
                    inter[slot * I + col] = (bf16_t)sv;
                }
            }
        }
    }
}

// ------------------------------- GEMM 2 -----------------------------------
// out[tok][c] (+)= w * (inter[slot] . down_col_c);  B = down_t [col][k]
// tile: 128 slots x 128 cols; waves 2x2, each 64x64.

template <bool EXPERT>
__global__ __launch_bounds__(256) void k_gemm2(const bf16_t* __restrict__ Ain,
                                               const bf16_t* __restrict__ WtBase,
                                               size_t estride,
                                               const int* __restrict__ slot_token,
                                               const float* __restrict__ slot_w,
                                               const int4* __restrict__ ttbl,
                                               const int* __restrict__ ntl,
                                               float* __restrict__ out) {
    int base_slot, rows, e;
    if (EXPERT) {
        if ((int)blockIdx.x >= *ntl) return;
        int4 tt = ttbl[blockIdx.x];
        base_slot = tt.x; rows = tt.y; e = tt.z;
    } else {
        base_slot = blockIdx.x * BM; rows = BM; e = 0;
    }
    int c0 = blockIdx.y * 128;
    const bf16_t* Wt = WtBase + (size_t)e * estride + (size_t)c0 * I;

    __shared__ bf16_t As[BM][BK + 8];
    __shared__ bf16_t Bs[BM][BK + 8];

    int tid = threadIdx.x, lane = tid & 63, wave = tid >> 6;
    int wm = wave >> 1, wn = wave & 1;
    f32x4 acc[4][4] = {};

    for (int k0 = 0; k0 < I; k0 += BK) {
#pragma unroll
        for (int i = 0; i < 4; i++) {
            int c = tid + i * 256;
            int r = c >> 3, cc = (c & 7) * 8;
            uint4 v = make_uint4(0, 0, 0, 0);
            if (r < rows)
                v = *(const uint4*)(Ain + (size_t)(base_slot + r) * I + k0 + cc);
            *(uint4*)(&As[r][cc]) = v;
        }
#pragma unroll
        for (int i = 0; i < 4; i++) {
            int c = tid + i * 256;
            int r = c >> 3, cc = (c & 7) * 8;
            *(uint4*)(&Bs[r][cc]) = *(const uint4*)(Wt + (size_t)r * I + k0 + cc);
        }
        __syncthreads();
        int kg = (lane >> 4) * 8;
#pragma unroll
        for (int kk = 0; kk < BK; kk += 32) {
            bf16x8 a[4], b[4];
#pragma unroll
            for (int m = 0; m < 4; m++)
                a[m] = *(const bf16x8*)(&As[wm * 64 + m * 16 + (lane & 15)][kk + kg]);
#pragma unroll
            for (int n = 0; n < 4; n++)
                b[n] = *(const bf16x8*)(&Bs[wn * 64 + n * 16 + (lane & 15)][kk + kg]);
#pragma unroll
            for (int m = 0; m < 4; m++)
#pragma unroll
                for (int n = 0; n < 4; n++)
                    acc[m][n] = __builtin_amdgcn_mfma_f32_16x16x32_bf16(a[m], b[n], acc[m][n], 0, 0, 0);
        }
        __syncthreads();
    }
#pragma unroll
    for (int m = 0; m < 4; m++) {
#pragma unroll
        for (int j = 0; j < 4; j++) {
            int r = wm * 64 + m * 16 + (lane >> 4) * 4 + j;
            if (r < rows) {
                int slot = base_slot + r;
#pragma unroll
                for (int n = 0; n < 4; n++) {
                    int col = c0 + wn * 64 + n * 16 + (lane & 15);
                    float v = acc[m][n][j];
                    if (EXPERT) {
                        int tok = slot_token[slot];
                        atomicAdd(&out[(size_t)tok * D + col], v * slot_w[slot]);
                    } else {
                        out[(size_t)slot * D + col] = v;
                    }
                }
            }
        }
    }
}

// ------------------------------- launcher ---------------------------------

extern "C" void kernel_launch(void* const* d_in, const int* in_sizes, int n_in,
                              void* d_out, int out_size, void* d_ws, size_t ws_size,
                              hipStream_t stream) {
    const float* x  = (const float*)d_in[0];
    const float* gw = (const float*)d_in[1];
    const float* eb = (const float*)d_in[2];
    const float* gu = (const float*)d_in[3];
    const float* dn = (const float*)d_in[4];
    const float* sg = (const float*)d_in[5];
    const float* su = (const float*)d_in[6];
    const float* sd = (const float*)d_in[7];

    float* out        = (float*)d_out;
    float* out_idx    = out + (size_t)NTOK * D;
    float* out_scores = out_idx + (size_t)NTOK * TK;

    char* w = (char*)d_ws;
    auto alloc = [&](size_t bytes) {
        char* p = w;
        w += (bytes + 255) & ~(size_t)255;
        return p;
    };
    bf16_t* xb      = (bf16_t*)alloc((size_t)NTOK * D * 2);
    bf16_t* gut     = (bf16_t*)alloc((size_t)E * 2 * I * D * 2);   // [E][2I][D]
    bf16_t* dnt     = (bf16_t*)alloc((size_t)E * D * I * 2);       // [E][D][I]
    bf16_t* sgt     = (bf16_t*)alloc((size_t)I * D * 2);           // [I][D]
    bf16_t* sut     = (bf16_t*)alloc((size_t)I * D * 2);
    bf16_t* sdt     = (bf16_t*)alloc((size_t)D * I * 2);           // [D][I]
    bf16_t* inter   = (bf16_t*)alloc((size_t)NK * I * 2);
    bf16_t* inter_s = (bf16_t*)alloc((size_t)NTOK * I * 2);
    float*  tkw     = (float*)alloc((size_t)NK * 4);
    int*    tke     = (int*)alloc((size_t)NK * 4);
    int*    stok    = (int*)alloc((size_t)NK * 4);
    float*  sw      = (float*)alloc((size_t)NK * 4);
    int*    counts  = (int*)alloc(E * 4);
    int*    offs    = (int*)alloc((E + 1) * 4);
    int*    curs    = (int*)alloc(E * 4);
    int4*   ttbl    = (int4*)alloc(MAX_TILES * 16);
    int*    ntl     = (int*)alloc(4);

    if ((size_t)(w - (char*)d_ws) > ws_size) {
        k_sentinel<<<1, 64, 0, stream>>>(out);
        return;
    }

    k_zero_meta<<<1, 64, 0, stream>>>(counts, curs, ntl);
    k_convert_x<<<(NTOK * D / 8 + 255) / 256, 256, 0, stream>>>(x, xb, NTOK * D / 8);
    // weights: [b][R][C] -> [b][C][R]
    k_transpose<<<dim3(2 * I / 32, D / 32, E), dim3(32, 8), 0, stream>>>(gu, gut, D, 2 * I);
    k_transpose<<<dim3(D / 32, I / 32, E), dim3(32, 8), 0, stream>>>(dn, dnt, I, D);
    k_transpose<<<dim3(I / 32, D / 32, 1), dim3(32, 8), 0, stream>>>(sg, sgt, D, I);
    k_transpose<<<dim3(I / 32, D / 32, 1), dim3(32, 8), 0, stream>>>(su, sut, D, I);
    k_transpose<<<dim3(D / 32, I / 32, 1), dim3(32, 8), 0, stream>>>(sd, sdt, I, D);

    k_router<<<NTOK, 256, 0, stream>>>(x, gw, eb, out_idx, out_scores, tkw, tke, counts);
    k_offsets<<<1, 64, 0, stream>>>(counts, offs, ttbl, ntl);
    k_scatter<<<NK / 256, 256, 0, stream>>>(tke, tkw, offs, curs, stok, sw);

    // shared MLP (plain stores initialize out), then routed experts (atomic add)
    k_gemm1<false><<<dim3(NTOK / BM, I / 64), 256, 0, stream>>>(
        xb, sgt, sut, 0, nullptr, nullptr, nullptr, inter_s);
    k_gemm2<false><<<dim3(NTOK / BM, D / 128), 256, 0, stream>>>(
        inter_s, sdt, 0, nullptr, nullptr, nullptr, nullptr, out);

    k_gemm1<true><<<dim3(MAX_TILES, I / 64), 256, 0, stream>>>(
        xb, gut, gut + (size_t)I * D, (size_t)2 * I * D, stok, ttbl, ntl, inter);
    k_gemm2<true><<<dim3(MAX_TILES, D / 128), 256, 0, stream>>>(
        inter, dnt, (size_t)D * I, stok, sw, ttbl, ntl, out);
}

// Round 2
// 2517.837 us; speedup vs baseline: 1.3464x; 1.3464x over previous
//
#include <hip/hip_runtime.h>
#include <hip/hip_bf16.h>
#include <math.h>

// ---------------------------------------------------------------------------
// MoE block: router + grouped-expert SwiGLU + shared SwiGLU MLP.
// Round 2: m97-class GEMMs (global_load_lds w16, 128x128 tile, BK=64),
//          interleaved gate/up weights, atomic-free epilogue via outS+finalize.
// ---------------------------------------------------------------------------

typedef __bf16 bf16_t;
typedef __bf16 bf16x8 __attribute__((ext_vector_type(8)));
typedef float  f32x4  __attribute__((ext_vector_type(4)));

constexpr int NTOK = 8192;          // B*S
constexpr int D    = 2048;
constexpr int E    = 32;
constexpr int I    = 1024;
constexpr int TK   = 8;             // TOP_K
constexpr int NK   = NTOK * TK;     // 65536 slots
constexpr int BM   = 128;
constexpr int BK   = 64;
constexpr int MAX_TILES = E + NK / BM;   // 544 worst-case row tiles
constexpr float RSCALE = 2.5f;

__device__ __forceinline__ void gload16(const void* g, void* lds) {
    __builtin_amdgcn_global_load_lds(
        (const __attribute__((address_space(1))) void*)g,
        (__attribute__((address_space(3))) void*)lds, 16, 0, 0);
}

// ------------------------------- utilities --------------------------------

__global__ __launch_bounds__(64) void k_zero_meta(int* counts, int* cursors, int* ntl) {
    int t = threadIdx.x;
    if (t < E) { counts[t] = 0; cursors[t] = 0; }
    if (t == 0) *ntl = 0;
}

__global__ __launch_bounds__(64) void k_sentinel(float* out) {
    if (threadIdx.x == 0) out[0] = 12345.0f;   // signals ws_size too small
}

// f32 -> bf16, 8 elems/thread
__global__ __launch_bounds__(256) void k_convert_x(const float* __restrict__ src,
                                                   bf16_t* __restrict__ dst, int n8) {
    int i = blockIdx.x * 256 + threadIdx.x;
    if (i >= n8) return;
    const float4* s = (const float4*)src;
    float4 a = s[(size_t)i * 2], b = s[(size_t)i * 2 + 1];
    bf16_t t[8] = {(bf16_t)a.x, (bf16_t)a.y, (bf16_t)a.z, (bf16_t)a.w,
                   (bf16_t)b.x, (bf16_t)b.y, (bf16_t)b.z, (bf16_t)b.w};
    *(uint4*)(dst + (size_t)i * 8) = *(const uint4*)t;
}

// batched transpose+convert: src [b][R][C] f32 -> dst [b][rc(C)][R] bf16
// MODE 0: rc=c | 1: gate/up interleave (c<I ? 2c : 2(c-I)+1) | 2: rc=2c | 3: rc=2c+1
template <int MODE>
__global__ __launch_bounds__(256) void k_transpose(const float* __restrict__ src,
                                                   bf16_t* __restrict__ dst,
                                                   int R, int C,
                                                   size_t srcMat, size_t dstMat) {
    __shared__ float t[32][33];
    int b = blockIdx.z;
    const float* s = src + (size_t)b * srcMat;
    bf16_t* d = dst + (size_t)b * dstMat;
    int c0 = blockIdx.x * 32, r0 = blockIdx.y * 32;
    int tx = threadIdx.x, ty = threadIdx.y;    // 32 x 8
#pragma unroll
    for (int yy = 0; yy < 4; yy++)
        t[ty + yy * 8][tx] = s[(size_t)(r0 + ty + yy * 8) * C + c0 + tx];
    __syncthreads();
#pragma unroll
    for (int yy = 0; yy < 4; yy++) {
        int c = c0 + ty + yy * 8;
        int rc = (MODE == 0) ? c
               : (MODE == 1) ? ((c < I) ? 2 * c : 2 * (c - I) + 1)
               : (MODE == 2) ? 2 * c : 2 * c + 1;
        d[(size_t)rc * R + r0 + tx] = (bf16_t)t[tx][ty + yy * 8];
    }
}

// ------------------------------- router -----------------------------------

__global__ __launch_bounds__(256) void k_router(const float* __restrict__ x,
                                                const float* __restrict__ gw,
                                                const float* __restrict__ eb,
                                                float* __restrict__ out_idx,
                                                float* __restrict__ out_scores,
                                                float* __restrict__ topk_w,
                                                int* __restrict__ tok_expert,
                                                int* __restrict__ counts) {
    int t = blockIdx.x;
    int tid = threadIdx.x;
    int e = tid & 31, part = tid >> 5;         // 8 parts x 256 d each
    const float* xr = x + (size_t)t * D;
    float partial = 0.f;
    int d0 = part * 256;
    for (int d = d0; d < d0 + 256; d++)
        partial += xr[d] * gw[(size_t)d * E + e];

    __shared__ float red[8][32];
    __shared__ float sc[32], sfr[32];
    red[part][e] = partial;
    __syncthreads();
    if (tid < 32) {
        float l = 0.f;
#pragma unroll
        for (int p = 0; p < 8; p++) l += red[p][tid];
        float s = 1.f / (1.f + expf(-l));
        sc[tid] = s;
        sfr[tid] = s + eb[tid];
        out_scores[(size_t)t * E + tid] = s;
    }
    __syncthreads();
    if (tid == 0) {
        float gs[8];
#pragma unroll
        for (int g = 0; g < 8; g++) {
            float m1 = -1e30f, m2 = -1e30f;
#pragma unroll
            for (int i = 0; i < 4; i++) {
                float v = sfr[g * 4 + i];
                if (v > m1) { m2 = m1; m1 = v; } else if (v > m2) m2 = v;
            }
            gs[g] = m1 + m2;
        }
        bool gsel[8] = {false, false, false, false, false, false, false, false};
        for (int it = 0; it < 4; it++) {
            int bi = -1; float bv = -1e30f;
            for (int g = 0; g < 8; g++)
                if (!gsel[g] && gs[g] > bv) { bv = gs[g]; bi = g; }
            gsel[bi] = true;
        }
        float masked[32];
        for (int i = 0; i < 32; i++) masked[i] = gsel[i >> 2] ? sfr[i] : -1e30f;
        int idx[TK]; float w[TK]; float wsum = 0.f;
        for (int k = 0; k < TK; k++) {
            int bi = 0; float bv = -1e30f;
            for (int i = 0; i < 32; i++)
                if (masked[i] > bv) { bv = masked[i]; bi = i; }
            masked[bi] = -1e30f;
            idx[k] = bi; w[k] = sc[bi]; wsum += w[k];
        }
        float inv = RSCALE / (wsum + 1e-20f);
        for (int k = 0; k < TK; k++) {
            out_idx[(size_t)t * TK + k] = (float)idx[k];
            topk_w[(size_t)t * TK + k] = w[k] * inv;
            tok_expert[(size_t)t * TK + k] = idx[k];
            atomicAdd(&counts[idx[k]], 1);
        }
    }
}

__global__ __launch_bounds__(64) void k_offsets(const int* __restrict__ counts,
                                                int* __restrict__ offs,
                                                int4* __restrict__ ttbl,
                                                int* __restrict__ ntl) {
    if (threadIdx.x != 0) return;
    int off = 0, nt = 0;
    for (int e = 0; e < E; e++) {
        offs[e] = off;
        int c = counts[e];
        for (int r = 0; r < c; r += BM) {
            ttbl[nt] = make_int4(off + r, min(BM, c - r), e, 0);
            nt++;
        }
        off += c;
    }
    offs[E] = off;
    *ntl = nt;
}

__global__ __launch_bounds__(256) void k_scatter(const int* __restrict__ tok_expert,
                                                 const int* __restrict__ offs,
                                                 int* __restrict__ cursors,
                                                 int* __restrict__ slot_token,
                                                 int* __restrict__ slot_inv) {
    int i = blockIdx.x * 256 + threadIdx.x;
    if (i >= NK) return;
    int e = tok_expert[i];
    int pos = offs[e] + atomicAdd(&cursors[e], 1);
    slot_token[pos] = i >> 3;   // TK = 8
    slot_inv[i] = pos;
}

// ------------------------------- GEMM (m97 structure) ----------------------
// C[128 x 128] tile, BK=64, 4 waves (2x2) each 64x64, global_load_lds w16.
// B is pre-transposed: Bt[e][N][K].
// EPI 0: SwiGLU pair-combine -> bf16 C[ld=N/2]  (gate=even cols, up=odd cols)
// EPI 1: bf16 store  (expert down-proj -> outS[slot][D])
// EPI 2: f32 store   (shared down-proj -> out[tok][D])

template <bool EXPERT, bool GATHER, int EPI>
__global__ __launch_bounds__(256) void k_mm(const bf16_t* __restrict__ A,
                                            const bf16_t* __restrict__ Bt,
                                            int K, size_t estride,
                                            const int* __restrict__ slot_token,
                                            const int4* __restrict__ ttbl,
                                            const int* __restrict__ ntl,
                                            void* __restrict__ C, int ldc) {
    int base_slot, rows, e;
    if (EXPERT) {
        if ((int)blockIdx.x >= *ntl) return;
        int4 tt = ttbl[blockIdx.x];
        base_slot = tt.x; rows = tt.y; e = tt.z;
    } else {
        base_slot = blockIdx.x * BM; rows = BM; e = 0;
    }
    int c0 = blockIdx.y * 128;
    const bf16_t* Bw = Bt + (size_t)e * estride + (size_t)c0 * K;

    __shared__ bf16_t As[BM][BK];   // linear: global_load_lds needs contiguity
    __shared__ bf16_t Bs[128][BK];

    int tid = threadIdx.x, lane = tid & 63, wave = tid >> 6;
    int wm = wave >> 1, wn = wave & 1;

    // precompute per-thread staging addresses (row layout fixed across K-steps)
    const bf16_t* gA[4]; const bf16_t* gB[4];
    bf16_t* lA[4]; bf16_t* lB[4];
#pragma unroll
    for (int i = 0; i < 4; i++) {
        int chunk = i * 4 + wave;               // 16 chunks of 8 rows
        int row = chunk * 8 + (lane >> 3);
        int arow = min(row, rows - 1);
        int tok = GATHER ? slot_token[base_slot + arow] : (base_slot + arow);
        gA[i] = A + (size_t)tok * K + (lane & 7) * 8;
        gB[i] = Bw + (size_t)row * K + (lane & 7) * 8;
        lA[i] = &As[0][0] + chunk * 512;        // wave-uniform base; +lane*16B in HW
        lB[i] = &Bs[0][0] + chunk * 512;
    }

    f32x4 acc[4][4] = {};
    int lr = lane & 15, hi = lane >> 4;

    for (int k0 = 0; k0 < K; k0 += BK) {
#pragma unroll
        for (int i = 0; i < 4; i++) {
            gload16(gA[i] + k0, lA[i]);
            gload16(gB[i] + k0, lB[i]);
        }
        __syncthreads();                        // drains vmcnt(0)
#pragma unroll
        for (int kk = 0; kk < BK; kk += 32) {
            bf16x8 af[4], bf[4];
            int kg = kk + hi * 8;
#pragma unroll
            for (int m = 0; m < 4; m++)
                af[m] = *(const bf16x8*)(&As[wm * 64 + m * 16 + lr][kg]);
#pragma unroll
            for (int n = 0; n < 4; n++)
                bf[n] = *(const bf16x8*)(&Bs[wn * 64 + n * 16 + lr][kg]);
#pragma unroll
            for (int m = 0; m < 4; m++)
#pragma unroll
                for (int n = 0; n < 4; n++)
                    acc[m][n] = __builtin_amdgcn_mfma_f32_16x16x32_bf16(af[m], bf[n], acc[m][n], 0, 0, 0);
        }
        __syncthreads();
    }

    // epilogue: C row r = wm*64+m*16+hi*4+j, col c = c0+wn*64+n*16+lr (m89 layout)
#pragma unroll
    for (int m = 0; m < 4; m++) {
#pragma unroll
        for (int j = 0; j < 4; j++) {
            int r = wm * 64 + m * 16 + hi * 4 + j;
            bool valid = !EXPERT || (r < rows);
            size_t orow = (size_t)base_slot + r;
#pragma unroll
            for (int n = 0; n < 4; n++) {
                float v = acc[m][n][j];
                if (EPI == 0) {
                    float o = __shfl_xor(v, 1);
                    float g = (lane & 1) ? o : v;
                    float u = (lane & 1) ? v : o;
                    float sv = g / (1.f + __expf(-g)) * u;
                    int c = c0 + wn * 64 + n * 16 + lr;
                    if (valid && !(lane & 1))
                        ((bf16_t*)C)[orow * ldc + (c >> 1)] = (bf16_t)sv;
                } else if (EPI == 1) {
                    int c = c0 + wn * 64 + n * 16 + lr;
                    if (valid) ((bf16_t*)C)[orow * ldc + c] = (bf16_t)v;
                } else {
                    int c = c0 + wn * 64 + n * 16 + lr;
                    if (valid) ((float*)C)[orow * ldc + c] = v;
                }
            }
        }
    }
}

// ------------------------------- finalize ----------------------------------
// out[tok][d] += sum_k w_k * outS[pos(tok,k)][d]   (out already = shared MLP)

__global__ __launch_bounds__(256) void k_finalize(const bf16_t* __restrict__ outS,
                                                  const int* __restrict__ slot_inv,
                                                  const float* __restrict__ tkw,
                                                  float* __restrict__ out) {
    int tok = blockIdx.x, tid = threadIdx.x;
    __shared__ int sp[TK];
    __shared__ float swt[TK];
    if (tid < TK) {
        sp[tid] = slot_inv[tok * TK + tid];
        swt[tid] = tkw[tok * TK + tid];
    }
    __syncthreads();
    int c = tid * 8;                 // 2048 / 256
    float* op = out + (size_t)tok * D + c;
    float acc[8];
    float4 o0 = *(float4*)op, o1 = *(float4*)(op + 4);
    acc[0] = o0.x; acc[1] = o0.y; acc[2] = o0.z; acc[3] = o0.w;
    acc[4] = o1.x; acc[5] = o1.y; acc[6] = o1.z; acc[7] = o1.w;
#pragma unroll
    for (int k = 0; k < TK; k++) {
        bf16x8 v = *(const bf16x8*)(outS + (size_t)sp[k] * D + c);
        float w = swt[k];
#pragma unroll
        for (int j = 0; j < 8; j++) acc[j] += w * (float)v[j];
    }
    o0 = make_float4(acc[0], acc[1], acc[2], acc[3]);
    o1 = make_float4(acc[4], acc[5], acc[6], acc[7]);
    *(float4*)op = o0;
    *(float4*)(op + 4) = o1;
}

// ------------------------------- launcher ---------------------------------

extern "C" void kernel_launch(void* const* d_in, const int* in_sizes, int n_in,
                              void* d_out, int out_size, void* d_ws, size_t ws_size,
                              hipStream_t stream) {
    const float* x  = (const float*)d_in[0];
    const float* gw = (const float*)d_in[1];
    const float* eb = (const float*)d_in[2];
    const float* gu = (const float*)d_in[3];
    const float* dn = (const float*)d_in[4];
    const float* sg = (const float*)d_in[5];
    const float* su = (const float*)d_in[6];
    const float* sd = (const float*)d_in[7];

    float* out        = (float*)d_out;
    float* out_idx    = out + (size_t)NTOK * D;
    float* out_scores = out_idx + (size_t)NTOK * TK;

    char* w = (char*)d_ws;
    auto alloc = [&](size_t bytes) {
        char* p = w;
        w += (bytes + 255) & ~(size_t)255;
        return p;
    };
    bf16_t* xb      = (bf16_t*)alloc((size_t)NTOK * D * 2);
    bf16_t* gut     = (bf16_t*)alloc((size_t)E * 2 * I * D * 2);   // [E][2I][D] interleaved
    bf16_t* dnt     = (bf16_t*)alloc((size_t)E * D * I * 2);       // [E][D][I]
    bf16_t* sh1t    = (bf16_t*)alloc((size_t)2 * I * D * 2);       // [2I][D] interleaved
    bf16_t* sdt     = (bf16_t*)alloc((size_t)D * I * 2);           // [D][I]
    bf16_t* inter   = (bf16_t*)alloc((size_t)NK * I * 2);
    bf16_t* inter_s = (bf16_t*)alloc((size_t)NTOK * I * 2);
    float*  tkw     = (float*)alloc((size_t)NK * 4);
    int*    tke     = (int*)alloc((size_t)NK * 4);
    int*    stok    = (int*)alloc((size_t)NK * 4);
    int*    sinv    = (int*)alloc((size_t)NK * 4);
    int*    counts  = (int*)alloc(E * 4);
    int*    offs    = (int*)alloc((E + 1) * 4);
    int*    curs    = (int*)alloc(E * 4);
    int4*   ttbl    = (int4*)alloc(MAX_TILES * 16);
    int*    ntl     = (int*)alloc(4);
    // outS[NK][D] bf16 (256MB) aliases gut (256MB): gut is dead after expert gemm1
    bf16_t* outS    = gut;

    if ((size_t)(w - (char*)d_ws) > ws_size) {
        k_sentinel<<<1, 64, 0, stream>>>(out);
        return;
    }

    k_zero_meta<<<1, 64, 0, stream>>>(counts, curs, ntl);
    k_convert_x<<<(NTOK * D / 8 + 255) / 256, 256, 0, stream>>>(x, xb, NTOK * D / 8);

    // weight reshapes
    k_transpose<1><<<dim3(2 * I / 32, D / 32, E), dim3(32, 8), 0, stream>>>(
        gu, gut, D, 2 * I, (size_t)D * 2 * I, (size_t)D * 2 * I);
    k_transpose<0><<<dim3(D / 32, I / 32, E), dim3(32, 8), 0, stream>>>(
        dn, dnt, I, D, (size_t)I * D, (size_t)I * D);
    k_transpose<2><<<dim3(I / 32, D / 32, 1), dim3(32, 8), 0, stream>>>(
        sg, sh1t, D, I, 0, 0);
    k_transpose<3><<<dim3(I / 32, D / 32, 1), dim3(32, 8), 0, stream>>>(
        su, sh1t, D, I, 0, 0);
    k_transpose<0><<<dim3(D / 32, I / 32, 1), dim3(32, 8), 0, stream>>>(
        sd, sdt, I, D, 0, 0);

    // routing
    k_router<<<NTOK, 256, 0, stream>>>(x, gw, eb, out_idx, out_scores, tkw, tke, counts);
    k_offsets<<<1, 64, 0, stream>>>(counts, offs, ttbl, ntl);
    k_scatter<<<NK / 256, 256, 0, stream>>>(tke, offs, curs, stok, sinv);

    // expert path (gemm1 must finish before outS overwrites gut)
    k_mm<true, true, 0><<<dim3(MAX_TILES, (2 * I) / 128), 256, 0, stream>>>(
        xb, gut, D, (size_t)2 * I * D, stok, ttbl, ntl, inter, I);
    k_mm<true, false, 1><<<dim3(MAX_TILES, D / 128), 256, 0, stream>>>(
        inter, dnt, I, (size_t)D * I, nullptr, ttbl, ntl, outS, D);

    // shared path
    k_mm<false, false, 0><<<dim3(NTOK / BM, (2 * I) / 128), 256, 0, stream>>>(
        xb, sh1t, D, 0, nullptr, nullptr, nullptr, inter_s, I);
    k_mm<false, false, 2><<<dim3(NTOK / BM, D / 128), 256, 0, stream>>>(
        inter_s, sdt, I, 0, nullptr, nullptr, nullptr, out, D);

    // combine
    k_finalize<<<NTOK, 256, 0, stream>>>(outS, sinv, tkw, out);
}

// Round 4
// 1903.180 us; speedup vs baseline: 1.7812x; 1.3230x over previous
//
#include <hip/hip_runtime.h>
#include <hip/hip_bf16.h>
#include <math.h>

// ---------------------------------------------------------------------------
// MoE block: router + grouped-expert SwiGLU + shared SwiGLU MLP.
// Round 4: 256x256 8-phase GEMM with CORRECTED wait protocol:
//   vmcnt(4) at end of P4/P8 *before* the end-barrier, so the barrier
//   publishes the drained loads to all waves before dependent ds_reads.
// ---------------------------------------------------------------------------

typedef __bf16 bf16_t;
typedef __bf16 bf16x8 __attribute__((ext_vector_type(8)));
typedef float  f32x4  __attribute__((ext_vector_type(4)));

constexpr int NTOK = 8192;          // B*S
constexpr int D    = 2048;
constexpr int E    = 32;
constexpr int I    = 1024;
constexpr int TK   = 8;             // TOP_K
constexpr int NK   = NTOK * TK;     // 65536 slots
constexpr int TM   = 256;           // GEMM row tile
constexpr int MAX_TILES = E + NK / TM;   // 288 worst-case row tiles
constexpr float RSCALE = 2.5f;

#define GL16(g, l) __builtin_amdgcn_global_load_lds( \
    (const __attribute__((address_space(1))) void*)(g), \
    (__attribute__((address_space(3))) void*)(l), 16, 0, 0)

// ------------------------------- utilities --------------------------------

__global__ __launch_bounds__(64) void k_zero_meta(int* counts, int* cursors, int* ntl) {
    int t = threadIdx.x;
    if (t < E) { counts[t] = 0; cursors[t] = 0; }
    if (t == 0) *ntl = 0;
}

__global__ __launch_bounds__(64) void k_sentinel(float* out) {
    if (threadIdx.x == 0) out[0] = 12345.0f;   // signals ws_size too small
}

// f32 -> bf16, 8 elems/thread
__global__ __launch_bounds__(256) void k_convert_x(const float* __restrict__ src,
                                                   bf16_t* __restrict__ dst, int n8) {
    int i = blockIdx.x * 256 + threadIdx.x;
    if (i >= n8) return;
    const float4* s = (const float4*)src;
    float4 a = s[(size_t)i * 2], b = s[(size_t)i * 2 + 1];
    bf16_t t[8] = {(bf16_t)a.x, (bf16_t)a.y, (bf16_t)a.z, (bf16_t)a.w,
                   (bf16_t)b.x, (bf16_t)b.y, (bf16_t)b.z, (bf16_t)b.w};
    *(uint4*)(dst + (size_t)i * 8) = *(const uint4*)t;
}

// batched transpose+convert: src [b][R][C] f32 -> dst [b][rc(C)][R] bf16
// MODE 0: rc=c | 1: gate/up interleave (c<I ? 2c : 2(c-I)+1) | 2: rc=2c | 3: rc=2c+1
template <int MODE>
__global__ __launch_bounds__(256) void k_transpose(const float* __restrict__ src,
                                                   bf16_t* __restrict__ dst,
                                                   int R, int C,
                                                   size_t srcMat, size_t dstMat) {
    __shared__ float t[32][33];
    int b = blockIdx.z;
    const float* s = src + (size_t)b * srcMat;
    bf16_t* d = dst + (size_t)b * dstMat;
    int c0 = blockIdx.x * 32, r0 = blockIdx.y * 32;
    int tx = threadIdx.x, ty = threadIdx.y;    // 32 x 8
#pragma unroll
    for (int yy = 0; yy < 4; yy++)
        t[ty + yy * 8][tx] = s[(size_t)(r0 + ty + yy * 8) * C + c0 + tx];
    __syncthreads();
#pragma unroll
    for (int yy = 0; yy < 4; yy++) {
        int c = c0 + ty + yy * 8;
        int rc = (MODE == 0) ? c
               : (MODE == 1) ? ((c < I) ? 2 * c : 2 * (c - I) + 1)
               : (MODE == 2) ? 2 * c : 2 * c + 1;
        d[(size_t)rc * R + r0 + tx] = (bf16_t)t[tx][ty + yy * 8];
    }
}

// ------------------------------- router -----------------------------------

__global__ __launch_bounds__(256) void k_router(const float* __restrict__ x,
                                                const float* __restrict__ gw,
                                                const float* __restrict__ eb,
                                                float* __restrict__ out_idx,
                                                float* __restrict__ out_scores,
                                                float* __restrict__ topk_w,
                                                int* __restrict__ tok_expert,
                                                int* __restrict__ counts) {
    int t = blockIdx.x;
    int tid = threadIdx.x;
    int e = tid & 31, part = tid >> 5;         // 8 parts x 256 d each
    const float* xr = x + (size_t)t * D;
    float partial = 0.f;
    int d0 = part * 256;
    for (int d = d0; d < d0 + 256; d++)
        partial += xr[d] * gw[(size_t)d * E + e];

    __shared__ float red[8][32];
    __shared__ float sc[32], sfr[32];
    red[part][e] = partial;
    __syncthreads();
    if (tid < 32) {
        float l = 0.f;
#pragma unroll
        for (int p = 0; p < 8; p++) l += red[p][tid];
        float s = 1.f / (1.f + expf(-l));
        sc[tid] = s;
        sfr[tid] = s + eb[tid];
        out_scores[(size_t)t * E + tid] = s;
    }
    __syncthreads();
    if (tid == 0) {
        float gs[8];
#pragma unroll
        for (int g = 0; g < 8; g++) {
            float m1 = -1e30f, m2 = -1e30f;
#pragma unroll
            for (int i = 0; i < 4; i++) {
                float v = sfr[g * 4 + i];
                if (v > m1) { m2 = m1; m1 = v; } else if (v > m2) m2 = v;
            }
            gs[g] = m1 + m2;
        }
        bool gsel[8] = {false, false, false, false, false, false, false, false};
        for (int it = 0; it < 4; it++) {
            int bi = -1; float bv = -1e30f;
            for (int g = 0; g < 8; g++)
                if (!gsel[g] && gs[g] > bv) { bv = gs[g]; bi = g; }
            gsel[bi] = true;
        }
        float masked[32];
        for (int i = 0; i < 32; i++) masked[i] = gsel[i >> 2] ? sfr[i] : -1e30f;
        int idx[TK]; float w[TK]; float wsum = 0.f;
        for (int k = 0; k < TK; k++) {
            int bi = 0; float bv = -1e30f;
            for (int i = 0; i < 32; i++)
                if (masked[i] > bv) { bv = masked[i]; bi = i; }
            masked[bi] = -1e30f;
            idx[k] = bi; w[k] = sc[bi]; wsum += w[k];
        }
        float inv = RSCALE / (wsum + 1e-20f);
        for (int k = 0; k < TK; k++) {
            out_idx[(size_t)t * TK + k] = (float)idx[k];
            topk_w[(size_t)t * TK + k] = w[k] * inv;
            tok_expert[(size_t)t * TK + k] = idx[k];
            atomicAdd(&counts[idx[k]], 1);
        }
    }
}

__global__ __launch_bounds__(64) void k_offsets(const int* __restrict__ counts,
                                                int* __restrict__ offs,
                                                int4* __restrict__ ttbl,
                                                int* __restrict__ ntl) {
    if (threadIdx.x != 0) return;
    int off = 0, nt = 0;
    for (int e = 0; e < E; e++) {
        offs[e] = off;
        int c = counts[e];
        for (int r = 0; r < c; r += TM) {
            ttbl[nt] = make_int4(off + r, min(TM, c - r), e, 0);
            nt++;
        }
        off += c;
    }
    offs[E] = off;
    *ntl = nt;
}

__global__ __launch_bounds__(256) void k_scatter(const int* __restrict__ tok_expert,
                                                 const int* __restrict__ offs,
                                                 int* __restrict__ cursors,
                                                 int* __restrict__ slot_token,
                                                 int* __restrict__ slot_inv) {
    int i = blockIdx.x * 256 + threadIdx.x;
    if (i >= NK) return;
    int e = tok_expert[i];
    int pos = offs[e] + atomicAdd(&cursors[e], 1);
    slot_token[pos] = i >> 3;   // TK = 8
    slot_inv[i] = pos;
}

// --------------------- 256x256 8-phase pipelined GEMM ----------------------
// 512 threads = 8 waves (2M x 4N); per-wave C = 128 rows x 64 cols.
// LDS 128 KiB: 2 buffers x (A[256][64] + B[256][64]) bf16, XOR-swizzled
// (16B chunk cb ^= row&7, applied on global source AND ds_read — rule #21).
//
// Stage plan, iteration j (tile t=2j in buf0, t+1 in buf1), 1 half/phase:
//   P1:A0(t+1)->buf1  P2:A1(t+1)->buf1  P3:B0(t+2)->buf0  P4:B1(t+2)->buf0
//   P5:A0(t+2)->buf0  P6:A1(t+2)->buf0  P7:B0(t+3)->buf1  P8:B1(t+3)->buf1
// Region lifetimes: buf A last ds_read at P3/P7, buf B at P2/P6; every stage
// is issued >= 1 end-barrier after its region's last read.  WAIT PROTOCOL:
// vmcnt(4) at END of P4 and P8 (before that end-barrier).  Outstanding there
// = 6 halves (12 ops); draining to 4 ops completes exactly the next tile's 4
// halves, and the end-barrier publishes them to ALL waves before the
// dependent ds_reads of P5/P1.  Loop never drains vmcnt to 0 (T4).

#define SCB() __builtin_amdgcn_sched_barrier(0)

#define P_MID() do { SCB(); __builtin_amdgcn_s_barrier(); \
    asm volatile("s_waitcnt lgkmcnt(0)" ::: "memory"); SCB(); \
    __builtin_amdgcn_s_setprio(1); } while (0)

#define P_END() do { __builtin_amdgcn_s_setprio(0); SCB(); \
    __builtin_amdgcn_s_barrier(); SCB(); } while (0)

#define P_END_VM4() do { __builtin_amdgcn_s_setprio(0); SCB(); \
    asm volatile("s_waitcnt vmcnt(4)" ::: "memory"); SCB(); \
    __builtin_amdgcn_s_barrier(); SCB(); } while (0)

#define STAGE_A(b, h, k0) do { \
    GL16(gA[h][0] + (k0), smb + (b) * 65536 + (h) * 16384 + w * 1024); \
    GL16(gA[h][1] + (k0), smb + (b) * 65536 + (h) * 16384 + 8192 + w * 1024); } while (0)

#define STAGE_B(b, h, k0) do { \
    GL16(gB[h][0] + (k0), smb + (b) * 65536 + 32768 + (h) * 16384 + w * 1024); \
    GL16(gB[h][1] + (k0), smb + (b) * 65536 + 32768 + (h) * 16384 + 8192 + w * 1024); } while (0)

#define LOAD_A(b, mh) do { _Pragma("unroll") for (int m_ = 0; m_ < 4; m_++) { \
    aF[m_][0] = *(const bf16x8*)(smb + (b) * 65536 + wm * 16384 + (mh) * 8192 + m_ * 2048 + lofs0); \
    aF[m_][1] = *(const bf16x8*)(smb + (b) * 65536 + wm * 16384 + (mh) * 8192 + m_ * 2048 + lofs1); } } while (0)

#define LOAD_B(b, nh) do { _Pragma("unroll") for (int n_ = 0; n_ < 2; n_++) { \
    bF[nh][n_][0] = *(const bf16x8*)(smb + (b) * 65536 + 32768 + wn * 8192 + (nh) * 4096 + n_ * 2048 + lofs0); \
    bF[nh][n_][1] = *(const bf16x8*)(smb + (b) * 65536 + 32768 + wn * 8192 + (nh) * 4096 + n_ * 2048 + lofs1); } } while (0)

#define MM(MH, NH) do { _Pragma("unroll") for (int m_ = 0; m_ < 4; m_++) \
    _Pragma("unroll") for (int n_ = 0; n_ < 2; n_++) { \
    acc[(MH) * 4 + m_][(NH) * 2 + n_] = __builtin_amdgcn_mfma_f32_16x16x32_bf16( \
        aF[m_][0], bF[NH][n_][0], acc[(MH) * 4 + m_][(NH) * 2 + n_], 0, 0, 0); \
    acc[(MH) * 4 + m_][(NH) * 2 + n_] = __builtin_amdgcn_mfma_f32_16x16x32_bf16( \
        aF[m_][1], bF[NH][n_][1], acc[(MH) * 4 + m_][(NH) * 2 + n_], 0, 0, 0); } } while (0)

template <bool EXPERT, bool GATHER, int EPI>
__global__ __launch_bounds__(512, 2) void k_mm8(const bf16_t* __restrict__ A,
                                                const bf16_t* __restrict__ Bt,
                                                int K, size_t estride,
                                                const int* __restrict__ slot_token,
                                                const int4* __restrict__ ttbl,
                                                const int* __restrict__ ntl,
                                                void* __restrict__ C, int ldc) {
    int base_slot, rows, e;
    if (EXPERT) {
        if ((int)blockIdx.y >= *ntl) return;
        int4 tt = ttbl[blockIdx.y];
        base_slot = tt.x; rows = tt.y; e = tt.z;
    } else {
        base_slot = blockIdx.y * TM; rows = TM; e = 0;
    }
    int c0 = blockIdx.x * 256;
    const bf16_t* Bw = Bt + (size_t)e * estride + (size_t)c0 * K;

    extern __shared__ char smb[];   // 128 KiB: [2][A 32K | B 32K]

    int tid = threadIdx.x, lane = tid & 63, w = tid >> 6;
    int wm = w >> 2, wn = w & 3;
    int lr = lane & 15, hi = lane >> 4;
    int rx = lr & 7;
    // swizzled ds_read lane offsets (16B chunk cb in [0,8), cb ^= row&7)
    int lofs0 = lr * 128 + ((hi ^ rx) << 4);
    int lofs1 = lr * 128 + (((4 + hi) ^ rx) << 4);

    // staging: row = h*128 + rnd*64 + tid/8; global chunk = (tid&7) ^ (row&7)
    int srow = tid >> 3;
    int cbg = (tid & 7) ^ (srow & 7);
    const bf16_t* gA[2][2]; const bf16_t* gB[2][2];
#pragma unroll
    for (int h = 0; h < 2; h++)
#pragma unroll
        for (int rnd = 0; rnd < 2; rnd++) {
            int r = h * 128 + rnd * 64 + srow;
            int ar = min(r, rows - 1);
            int tok = GATHER ? slot_token[base_slot + ar] : (base_slot + ar);
            gA[h][rnd] = A + (size_t)tok * K + cbg * 8;
            gB[h][rnd] = Bw + (size_t)r * K + cbg * 8;
        }

    f32x4 acc[8][4] = {};
    bf16x8 aF[4][2], bF[2][2][2];

    // prologue: buf0 <- tile0 (8 ops), buf1 <- tile1 B (4 ops); drain to 4;
    // barrier publishes tile0 to all waves before P1's ds_reads.
    STAGE_B(0, 0, 0); STAGE_B(0, 1, 0);
    STAGE_A(0, 0, 0); STAGE_A(0, 1, 0);
    STAGE_B(1, 0, 64); STAGE_B(1, 1, 64);
    SCB();
    asm volatile("s_waitcnt vmcnt(4)" ::: "memory");
    SCB();
    __builtin_amdgcn_s_barrier();
    SCB();

    int nt = K >> 6;                 // K/64, even (16 or 32)
    for (int kt = 0; kt < nt; kt += 2) {
        int k1 = (kt + 1) << 6;
        int k2 = (kt + 2 < nt) ? (kt + 2) << 6 : 0;   // wrapped, never read
        int k3 = (kt + 3 < nt) ? (kt + 3) << 6 : 0;
        // P1
        LOAD_A(0, 0); LOAD_B(0, 0);
        STAGE_A(1, 0, k1);
        P_MID(); MM(0, 0); P_END();
        // P2
        LOAD_B(0, 1);
        STAGE_A(1, 1, k1);
        P_MID(); MM(0, 1); P_END();
        // P3
        LOAD_A(0, 1);
        STAGE_B(0, 0, k2);
        P_MID(); MM(1, 0); P_END();
        // P4
        STAGE_B(0, 1, k2);
        P_MID(); MM(1, 1); P_END_VM4();
        // P5
        LOAD_A(1, 0); LOAD_B(1, 0);
        STAGE_A(0, 0, k2);
        P_MID(); MM(0, 0); P_END();
        // P6
        LOAD_B(1, 1);
        STAGE_A(0, 1, k2);
        P_MID(); MM(0, 1); P_END();
        // P7
        LOAD_A(1, 1);
        STAGE_B(1, 0, k3);
        P_MID(); MM(1, 0); P_END();
        // P8
        STAGE_B(1, 1, k3);
        P_MID(); MM(1, 1); P_END_VM4();
    }

    // epilogue: C row r = wm*128 + mi*16 + hi*4 + j, col = c0 + wn*64 + f*16 + lr
#pragma unroll
    for (int mi = 0; mi < 8; mi++) {
#pragma unroll
        for (int j = 0; j < 4; j++) {
            int r = wm * 128 + mi * 16 + hi * 4 + j;
            bool valid = !EXPERT || (r < rows);
            size_t orow = (size_t)base_slot + r;
#pragma unroll
            for (int f = 0; f < 4; f++) {
                float v = acc[mi][f][j];
                int c = c0 + wn * 64 + f * 16 + lr;
                if (EPI == 0) {
                    float o = __shfl_xor(v, 1);
                    float g = (lane & 1) ? o : v;
                    float u = (lane & 1) ? v : o;
                    float sv = g / (1.f + __expf(-g)) * u;
                    if (valid && !(lane & 1))
                        ((bf16_t*)C)[orow * ldc + (c >> 1)] = (bf16_t)sv;
                } else if (EPI == 1) {
                    float o = __shfl_xor(v, 1);
                    if (valid && !(lane & 1)) {
                        bf16_t pr[2] = {(bf16_t)v, (bf16_t)o};
                        *(unsigned int*)((bf16_t*)C + orow * ldc + c) = *(unsigned int*)pr;
                    }
                } else {
                    if (valid) ((float*)C)[orow * ldc + c] = v;
                }
            }
        }
    }
}

// ------------------------------- finalize ----------------------------------
// out[tok][d] += sum_k w_k * outS[pos(tok,k)][d]   (out already = shared MLP)

__global__ __launch_bounds__(256) void k_finalize(const bf16_t* __restrict__ outS,
                                                  const int* __restrict__ slot_inv,
                                                  const float* __restrict__ tkw,
                                                  float* __restrict__ out) {
    int tok = blockIdx.x, tid = threadIdx.x;
    __shared__ int sp[TK];
    __shared__ float swt[TK];
    if (tid < TK) {
        sp[tid] = slot_inv[tok * TK + tid];
        swt[tid] = tkw[tok * TK + tid];
    }
    __syncthreads();
    int c = tid * 8;                 // 2048 / 256
    float* op = out + (size_t)tok * D + c;
    float acc[8];
    float4 o0 = *(float4*)op, o1 = *(float4*)(op + 4);
    acc[0] = o0.x; acc[1] = o0.y; acc[2] = o0.z; acc[3] = o0.w;
    acc[4] = o1.x; acc[5] = o1.y; acc[6] = o1.z; acc[7] = o1.w;
#pragma unroll
    for (int k = 0; k < TK; k++) {
        bf16x8 v = *(const bf16x8*)(outS + (size_t)sp[k] * D + c);
        float w = swt[k];
#pragma unroll
        for (int j = 0; j < 8; j++) acc[j] += w * (float)v[j];
    }
    o0 = make_float4(acc[0], acc[1], acc[2], acc[3]);
    o1 = make_float4(acc[4], acc[5], acc[6], acc[7]);
    *(float4*)op = o0;
    *(float4*)(op + 4) = o1;
}

// ------------------------------- launcher ---------------------------------

extern "C" void kernel_launch(void* const* d_in, const int* in_sizes, int n_in,
                              void* d_out, int out_size, void* d_ws, size_t ws_size,
                              hipStream_t stream) {
    const float* x  = (const float*)d_in[0];
    const float* gw = (const float*)d_in[1];
    const float* eb = (const float*)d_in[2];
    const float* gu = (const float*)d_in[3];
    const float* dn = (const float*)d_in[4];
    const float* sg = (const float*)d_in[5];
    const float* su = (const float*)d_in[6];
    const float* sd = (const float*)d_in[7];

    float* out        = (float*)d_out;
    float* out_idx    = out + (size_t)NTOK * D;
    float* out_scores = out_idx + (size_t)NTOK * TK;

    char* w = (char*)d_ws;
    auto alloc = [&](size_t bytes) {
        char* p = w;
        w += (bytes + 255) & ~(size_t)255;
        return p;
    };
    bf16_t* xb      = (bf16_t*)alloc((size_t)NTOK * D * 2);
    bf16_t* gut     = (bf16_t*)alloc((size_t)E * 2 * I * D * 2);   // [E][2I][D] interleaved
    bf16_t* dnt     = (bf16_t*)alloc((size_t)E * D * I * 2);       // [E][D][I]
    bf16_t* sh1t    = (bf16_t*)alloc((size_t)2 * I * D * 2);       // [2I][D] interleaved
    bf16_t* sdt     = (bf16_t*)alloc((size_t)D * I * 2);           // [D][I]
    bf16_t* inter   = (bf16_t*)alloc((size_t)NK * I * 2);
    bf16_t* inter_s = (bf16_t*)alloc((size_t)NTOK * I * 2);
    float*  tkw     = (float*)alloc((size_t)NK * 4);
    int*    tke     = (int*)alloc((size_t)NK * 4);
    int*    stok    = (int*)alloc((size_t)NK * 4);
    int*    sinv    = (int*)alloc((size_t)NK * 4);
    int*    counts  = (int*)alloc(E * 4);
    int*    offs    = (int*)alloc((E + 1) * 4);
    int*    curs    = (int*)alloc(E * 4);
    int4*   ttbl    = (int4*)alloc(MAX_TILES * 16);
    int*    ntl     = (int*)alloc(4);
    // outS[NK][D] bf16 (256MB) aliases gut (256MB): gut is dead after expert gemm1
    bf16_t* outS    = gut;

    if ((size_t)(w - (char*)d_ws) > ws_size) {
        k_sentinel<<<1, 64, 0, stream>>>(out);
        return;
    }

    k_zero_meta<<<1, 64, 0, stream>>>(counts, curs, ntl);
    k_convert_x<<<(NTOK * D / 8 + 255) / 256, 256, 0, stream>>>(x, xb, NTOK * D / 8);

    // weight reshapes
    k_transpose<1><<<dim3(2 * I / 32, D / 32, E), dim3(32, 8), 0, stream>>>(
        gu, gut, D, 2 * I, (size_t)D * 2 * I, (size_t)D * 2 * I);
    k_transpose<0><<<dim3(D / 32, I / 32, E), dim3(32, 8), 0, stream>>>(
        dn, dnt, I, D, (size_t)I * D, (size_t)I * D);
    k_transpose<2><<<dim3(I / 32, D / 32, 1), dim3(32, 8), 0, stream>>>(
        sg, sh1t, D, I, 0, 0);
    k_transpose<3><<<dim3(I / 32, D / 32, 1), dim3(32, 8), 0, stream>>>(
        su, sh1t, D, I, 0, 0);
    k_transpose<0><<<dim3(D / 32, I / 32, 1), dim3(32, 8), 0, stream>>>(
        sd, sdt, I, D, 0, 0);

    // routing
    k_router<<<NTOK, 256, 0, stream>>>(x, gw, eb, out_idx, out_scores, tkw, tke, counts);
    k_offsets<<<1, 64, 0, stream>>>(counts, offs, ttbl, ntl);
    k_scatter<<<NK / 256, 256, 0, stream>>>(tke, offs, curs, stok, sinv);

    constexpr size_t SMEM = 131072;
    // expert path (gemm1 must finish before outS overwrites gut)
    k_mm8<true, true, 0><<<dim3(8, MAX_TILES), 512, SMEM, stream>>>(
        xb, gut, D, (size_t)2 * I * D, stok, ttbl, ntl, inter, I);
    k_mm8<true, false, 1><<<dim3(8, MAX_TILES), 512, SMEM, stream>>>(
        inter, dnt, I, (size_t)D * I, stok, ttbl, ntl, outS, D);

    // shared path
    k_mm8<false, false, 0><<<dim3(8, NTOK / TM), 512, SMEM, stream>>>(
        xb, sh1t, D, 0, nullptr, nullptr, nullptr, inter_s, I);
    k_mm8<false, false, 2><<<dim3(8, NTOK / TM), 512, SMEM, stream>>>(
        inter_s, sdt, I, 0, nullptr, nullptr, nullptr, out, D);

    // combine
    k_finalize<<<NTOK, 256, 0, stream>>>(outS, sinv, tkw, out);
}

// Round 5
// 1889.482 us; speedup vs baseline: 1.7941x; 1.0073x over previous
//
#include <hip/hip_runtime.h>
#include <hip/hip_bf16.h>
#include <math.h>

// ---------------------------------------------------------------------------
// MoE block: router + grouped-expert SwiGLU + shared SwiGLU MLP.
// Round 5: drop the explicit lgkmcnt(0)+SCB pinning inside phases; plain-C++
// ds_reads let the compiler emit counted lgkmcnt so reads drain UNDER the
// MFMA cluster. Minimal fences kept: SCB after each barrier (publish fence),
// vmcnt(4) with memory clobber (stage accounting), setprio bracket (T5).
// ---------------------------------------------------------------------------

typedef __bf16 bf16_t;
typedef __bf16 bf16x8 __attribute__((ext_vector_type(8)));
typedef float  f32x4  __attribute__((ext_vector_type(4)));

constexpr int NTOK = 8192;          // B*S
constexpr int D    = 2048;
constexpr int E    = 32;
constexpr int I    = 1024;
constexpr int TK   = 8;             // TOP_K
constexpr int NK   = NTOK * TK;     // 65536 slots
constexpr int TM   = 256;           // GEMM row tile
constexpr int MAX_TILES = E + NK / TM;   // 288 worst-case row tiles
constexpr float RSCALE = 2.5f;

#define GL16(g, l) __builtin_amdgcn_global_load_lds( \
    (const __attribute__((address_space(1))) void*)(g), \
    (__attribute__((address_space(3))) void*)(l), 16, 0, 0)

// ------------------------------- utilities --------------------------------

__global__ __launch_bounds__(64) void k_zero_meta(int* counts, int* cursors, int* ntl) {
    int t = threadIdx.x;
    if (t < E) { counts[t] = 0; cursors[t] = 0; }
    if (t == 0) *ntl = 0;
}

__global__ __launch_bounds__(64) void k_sentinel(float* out) {
    if (threadIdx.x == 0) out[0] = 12345.0f;   // signals ws_size too small
}

// f32 -> bf16, 8 elems/thread
__global__ __launch_bounds__(256) void k_convert_x(const float* __restrict__ src,
                                                   bf16_t* __restrict__ dst, int n8) {
    int i = blockIdx.x * 256 + threadIdx.x;
    if (i >= n8) return;
    const float4* s = (const float4*)src;
    float4 a = s[(size_t)i * 2], b = s[(size_t)i * 2 + 1];
    bf16_t t[8] = {(bf16_t)a.x, (bf16_t)a.y, (bf16_t)a.z, (bf16_t)a.w,
                   (bf16_t)b.x, (bf16_t)b.y, (bf16_t)b.z, (bf16_t)b.w};
    *(uint4*)(dst + (size_t)i * 8) = *(const uint4*)t;
}

// batched transpose+convert: src [b][R][C] f32 -> dst [b][rc(C)][R] bf16
// MODE 0: rc=c | 1: gate/up interleave (c<I ? 2c : 2(c-I)+1) | 2: rc=2c | 3: rc=2c+1
template <int MODE>
__global__ __launch_bounds__(256) void k_transpose(const float* __restrict__ src,
                                                   bf16_t* __restrict__ dst,
                                                   int R, int C,
                                                   size_t srcMat, size_t dstMat) {
    __shared__ float t[32][33];
    int b = blockIdx.z;
    const float* s = src + (size_t)b * srcMat;
    bf16_t* d = dst + (size_t)b * dstMat;
    int c0 = blockIdx.x * 32, r0 = blockIdx.y * 32;
    int tx = threadIdx.x, ty = threadIdx.y;    // 32 x 8
#pragma unroll
    for (int yy = 0; yy < 4; yy++)
        t[ty + yy * 8][tx] = s[(size_t)(r0 + ty + yy * 8) * C + c0 + tx];
    __syncthreads();
#pragma unroll
    for (int yy = 0; yy < 4; yy++) {
        int c = c0 + ty + yy * 8;
        int rc = (MODE == 0) ? c
               : (MODE == 1) ? ((c < I) ? 2 * c : 2 * (c - I) + 1)
               : (MODE == 2) ? 2 * c : 2 * c + 1;
        d[(size_t)rc * R + r0 + tx] = (bf16_t)t[tx][ty + yy * 8];
    }
}

// ------------------------------- router -----------------------------------

__global__ __launch_bounds__(256) void k_router(const float* __restrict__ x,
                                                const float* __restrict__ gw,
                                                const float* __restrict__ eb,
                                                float* __restrict__ out_idx,
                                                float* __restrict__ out_scores,
                                                float* __restrict__ topk_w,
                                                int* __restrict__ tok_expert,
                                                int* __restrict__ counts) {
    int t = blockIdx.x;
    int tid = threadIdx.x;
    int e = tid & 31, part = tid >> 5;         // 8 parts x 256 d each
    const float* xr = x + (size_t)t * D;
    float partial = 0.f;
    int d0 = part * 256;
    for (int d = d0; d < d0 + 256; d++)
        partial += xr[d] * gw[(size_t)d * E + e];

    __shared__ float red[8][32];
    __shared__ float sc[32], sfr[32];
    red[part][e] = partial;
    __syncthreads();
    if (tid < 32) {
        float l = 0.f;
#pragma unroll
        for (int p = 0; p < 8; p++) l += red[p][tid];
        float s = 1.f / (1.f + expf(-l));
        sc[tid] = s;
        sfr[tid] = s + eb[tid];
        out_scores[(size_t)t * E + tid] = s;
    }
    __syncthreads();
    if (tid == 0) {
        float gs[8];
#pragma unroll
        for (int g = 0; g < 8; g++) {
            float m1 = -1e30f, m2 = -1e30f;
#pragma unroll
            for (int i = 0; i < 4; i++) {
                float v = sfr[g * 4 + i];
                if (v > m1) { m2 = m1; m1 = v; } else if (v > m2) m2 = v;
            }
            gs[g] = m1 + m2;
        }
        bool gsel[8] = {false, false, false, false, false, false, false, false};
        for (int it = 0; it < 4; it++) {
            int bi = -1; float bv = -1e30f;
            for (int g = 0; g < 8; g++)
                if (!gsel[g] && gs[g] > bv) { bv = gs[g]; bi = g; }
            gsel[bi] = true;
        }
        float masked[32];
        for (int i = 0; i < 32; i++) masked[i] = gsel[i >> 2] ? sfr[i] : -1e30f;
        int idx[TK]; float w[TK]; float wsum = 0.f;
        for (int k = 0; k < TK; k++) {
            int bi = 0; float bv = -1e30f;
            for (int i = 0; i < 32; i++)
                if (masked[i] > bv) { bv = masked[i]; bi = i; }
            masked[bi] = -1e30f;
            idx[k] = bi; w[k] = sc[bi]; wsum += w[k];
        }
        float inv = RSCALE / (wsum + 1e-20f);
        for (int k = 0; k < TK; k++) {
            out_idx[(size_t)t * TK + k] = (float)idx[k];
            topk_w[(size_t)t * TK + k] = w[k] * inv;
            tok_expert[(size_t)t * TK + k] = idx[k];
            atomicAdd(&counts[idx[k]], 1);
        }
    }
}

__global__ __launch_bounds__(64) void k_offsets(const int* __restrict__ counts,
                                                int* __restrict__ offs,
                                                int4* __restrict__ ttbl,
                                                int* __restrict__ ntl) {
    if (threadIdx.x != 0) return;
    int off = 0, nt = 0;
    for (int e = 0; e < E; e++) {
        offs[e] = off;
        int c = counts[e];
        for (int r = 0; r < c; r += TM) {
            ttbl[nt] = make_int4(off + r, min(TM, c - r), e, 0);
            nt++;
        }
        off += c;
    }
    offs[E] = off;
    *ntl = nt;
}

__global__ __launch_bounds__(256) void k_scatter(const int* __restrict__ tok_expert,
                                                 const int* __restrict__ offs,
                                                 int* __restrict__ cursors,
                                                 int* __restrict__ slot_token,
                                                 int* __restrict__ slot_inv) {
    int i = blockIdx.x * 256 + threadIdx.x;
    if (i >= NK) return;
    int e = tok_expert[i];
    int pos = offs[e] + atomicAdd(&cursors[e], 1);
    slot_token[pos] = i >> 3;   // TK = 8
    slot_inv[i] = pos;
}

// --------------------- 256x256 8-phase pipelined GEMM ----------------------
// 512 threads = 8 waves (2M x 4N); per-wave C = 128 rows x 64 cols.
// LDS 128 KiB: 2 buffers x (A[256][64] + B[256][64]) bf16, XOR-swizzled
// (16B chunk cb ^= row&7, applied on global source AND ds_read — rule #21).
//
// Stage plan, iteration j (tile t=2j in buf0, t+1 in buf1), 1 half/phase:
//   P1:A0(t+1)->buf1  P2:A1(t+1)->buf1  P3:B0(t+2)->buf0  P4:B1(t+2)->buf0
//   P5:A0(t+2)->buf0  P6:A1(t+2)->buf0  P7:B0(t+3)->buf1  P8:B1(t+3)->buf1
// vmcnt(4) at END of P4/P8 before the end-barrier: outstanding there = 12
// ops, draining to 4 completes exactly the next tile's 4 halves; the barrier
// publishes them to all waves.  Loop never drains vmcnt to 0 (T4).
//
// Fencing (round-5): NO explicit lgkmcnt(0) — ds_reads are plain C++ loads,
// the compiler emits counted lgkmcnt so reads drain under the MFMA cluster.
// SCB only right after each s_barrier (prevents ds_read hoisting above the
// publish point).  vmcnt asm has a memory clobber so GL16s cannot cross it
// (keeps the vmcnt accounting exact).

#define SCB() __builtin_amdgcn_sched_barrier(0)

#define P_MID() do { __builtin_amdgcn_s_barrier(); SCB(); \
    __builtin_amdgcn_s_setprio(1); } while (0)

#define P_END() do { __builtin_amdgcn_s_setprio(0); \
    __builtin_amdgcn_s_barrier(); SCB(); } while (0)

#define P_END_VM4() do { __builtin_amdgcn_s_setprio(0); \
    asm volatile("s_waitcnt vmcnt(4)" ::: "memory"); \
    __builtin_amdgcn_s_barrier(); SCB(); } while (0)

#define STAGE_A(b, h, k0) do { \
    GL16(gA[h][0] + (k0), smb + (b) * 65536 + (h) * 16384 + w * 1024); \
    GL16(gA[h][1] + (k0), smb + (b) * 65536 + (h) * 16384 + 8192 + w * 1024); } while (0)

#define STAGE_B(b, h, k0) do { \
    GL16(gB[h][0] + (k0), smb + (b) * 65536 + 32768 + (h) * 16384 + w * 1024); \
    GL16(gB[h][1] + (k0), smb + (b) * 65536 + 32768 + (h) * 16384 + 8192 + w * 1024); } while (0)

#define LOAD_A(b, mh) do { _Pragma("unroll") for (int m_ = 0; m_ < 4; m_++) { \
    aF[m_][0] = *(const bf16x8*)(smb + (b) * 65536 + wm * 16384 + (mh) * 8192 + m_ * 2048 + lofs0); \
    aF[m_][1] = *(const bf16x8*)(smb + (b) * 65536 + wm * 16384 + (mh) * 8192 + m_ * 2048 + lofs1); } } while (0)

#define LOAD_B(b, nh) do { _Pragma("unroll") for (int n_ = 0; n_ < 2; n_++) { \
    bF[nh][n_][0] = *(const bf16x8*)(smb + (b) * 65536 + 32768 + wn * 8192 + (nh) * 4096 + n_ * 2048 + lofs0); \
    bF[nh][n_][1] = *(const bf16x8*)(smb + (b) * 65536 + 32768 + wn * 8192 + (nh) * 4096 + n_ * 2048 + lofs1); } } while (0)

#define MM(MH, NH) do { _Pragma("unroll") for (int m_ = 0; m_ < 4; m_++) \
    _Pragma("unroll") for (int n_ = 0; n_ < 2; n_++) { \
    acc[(MH) * 4 + m_][(NH) * 2 + n_] = __builtin_amdgcn_mfma_f32_16x16x32_bf16( \
        aF[m_][0], bF[NH][n_][0], acc[(MH) * 4 + m_][(NH) * 2 + n_], 0, 0, 0); \
    acc[(MH) * 4 + m_][(NH) * 2 + n_] = __builtin_amdgcn_mfma_f32_16x16x32_bf16( \
        aF[m_][1], bF[NH][n_][1], acc[(MH) * 4 + m_][(NH) * 2 + n_], 0, 0, 0); } } while (0)

template <bool EXPERT, bool GATHER, int EPI>
__global__ __launch_bounds__(512, 2) void k_mm8(const bf16_t* __restrict__ A,
                                                const bf16_t* __restrict__ Bt,
                                                int K, size_t estride,
                                                const int* __restrict__ slot_token,
                                                const int4* __restrict__ ttbl,
                                                const int* __restrict__ ntl,
                                                void* __restrict__ C, int ldc) {
    int base_slot, rows, e;
    if (EXPERT) {
        if ((int)blockIdx.y >= *ntl) return;
        int4 tt = ttbl[blockIdx.y];
        base_slot = tt.x; rows = tt.y; e = tt.z;
    } else {
        base_slot = blockIdx.y * TM; rows = TM; e = 0;
    }
    int c0 = blockIdx.x * 256;
    const bf16_t* Bw = Bt + (size_t)e * estride + (size_t)c0 * K;

    extern __shared__ char smb[];   // 128 KiB: [2][A 32K | B 32K]

    int tid = threadIdx.x, lane = tid & 63, w = tid >> 6;
    int wm = w >> 2, wn = w & 3;
    int lr = lane & 15, hi = lane >> 4;
    int rx = lr & 7;
    // swizzled ds_read lane offsets (16B chunk cb in [0,8), cb ^= row&7)
    int lofs0 = lr * 128 + ((hi ^ rx) << 4);
    int lofs1 = lr * 128 + (((4 + hi) ^ rx) << 4);

    // staging: row = h*128 + rnd*64 + tid/8; global chunk = (tid&7) ^ (row&7)
    int srow = tid >> 3;
    int cbg = (tid & 7) ^ (srow & 7);
    const bf16_t* gA[2][2]; const bf16_t* gB[2][2];
#pragma unroll
    for (int h = 0; h < 2; h++)
#pragma unroll
        for (int rnd = 0; rnd < 2; rnd++) {
            int r = h * 128 + rnd * 64 + srow;
            int ar = min(r, rows - 1);
            int tok = GATHER ? slot_token[base_slot + ar] : (base_slot + ar);
            gA[h][rnd] = A + (size_t)tok * K + cbg * 8;
            gB[h][rnd] = Bw + (size_t)r * K + cbg * 8;
        }

    f32x4 acc[8][4] = {};
    bf16x8 aF[4][2], bF[2][2][2];

    // prologue: buf0 <- tile0 (8 ops), buf1 <- tile1 B (4 ops); drain to 4;
    // barrier publishes tile0 to all waves before P1's ds_reads.
    STAGE_B(0, 0, 0); STAGE_B(0, 1, 0);
    STAGE_A(0, 0, 0); STAGE_A(0, 1, 0);
    STAGE_B(1, 0, 64); STAGE_B(1, 1, 64);
    asm volatile("s_waitcnt vmcnt(4)" ::: "memory");
    __builtin_amdgcn_s_barrier();
    SCB();

    int nt = K >> 6;                 // K/64, even (16 or 32)
    for (int kt = 0; kt < nt; kt += 2) {
        int k1 = (kt + 1) << 6;
        int k2 = (kt + 2 < nt) ? (kt + 2) << 6 : 0;   // wrapped, never read
        int k3 = (kt + 3 < nt) ? (kt + 3) << 6 : 0;
        // P1
        LOAD_A(0, 0); LOAD_B(0, 0);
        STAGE_A(1, 0, k1);
        P_MID(); MM(0, 0); P_END();
        // P2
        LOAD_B(0, 1);
        STAGE_A(1, 1, k1);
        P_MID(); MM(0, 1); P_END();
        // P3
        LOAD_A(0, 1);
        STAGE_B(0, 0, k2);
        P_MID(); MM(1, 0); P_END();
        // P4
        STAGE_B(0, 1, k2);
        P_MID(); MM(1, 1); P_END_VM4();
        // P5
        LOAD_A(1, 0); LOAD_B(1, 0);
        STAGE_A(0, 0, k2);
        P_MID(); MM(0, 0); P_END();
        // P6
        LOAD_B(1, 1);
        STAGE_A(0, 1, k2);
        P_MID(); MM(0, 1); P_END();
        // P7
        LOAD_A(1, 1);
        STAGE_B(1, 0, k3);
        P_MID(); MM(1, 0); P_END();
        // P8
        STAGE_B(1, 1, k3);
        P_MID(); MM(1, 1); P_END_VM4();
    }

    // epilogue: C row r = wm*128 + mi*16 + hi*4 + j, col = c0 + wn*64 + f*16 + lr
#pragma unroll
    for (int mi = 0; mi < 8; mi++) {
#pragma unroll
        for (int j = 0; j < 4; j++) {
            int r = wm * 128 + mi * 16 + hi * 4 + j;
            bool valid = !EXPERT || (r < rows);
            size_t orow = (size_t)base_slot + r;
#pragma unroll
            for (int f = 0; f < 4; f++) {
                float v = acc[mi][f][j];
                int c = c0 + wn * 64 + f * 16 + lr;
                if (EPI == 0) {
                    float o = __shfl_xor(v, 1);
                    float g = (lane & 1) ? o : v;
                    float u = (lane & 1) ? v : o;
                    float sv = g / (1.f + __expf(-g)) * u;
                    if (valid && !(lane & 1))
                        ((bf16_t*)C)[orow * ldc + (c >> 1)] = (bf16_t)sv;
                } else if (EPI == 1) {
                    float o = __shfl_xor(v, 1);
                    if (valid && !(lane & 1)) {
                        bf16_t pr[2] = {(bf16_t)v, (bf16_t)o};
                        *(unsigned int*)((bf16_t*)C + orow * ldc + c) = *(unsigned int*)pr;
                    }
                } else {
                    if (valid) ((float*)C)[orow * ldc + c] = v;
                }
            }
        }
    }
}

// ------------------------------- finalize ----------------------------------
// out[tok][d] += sum_k w_k * outS[pos(tok,k)][d]   (out already = shared MLP)

__global__ __launch_bounds__(256) void k_finalize(const bf16_t* __restrict__ outS,
                                                  const int* __restrict__ slot_inv,
                                                  const float* __restrict__ tkw,
                                                  float* __restrict__ out) {
    int tok = blockIdx.x, tid = threadIdx.x;
    __shared__ int sp[TK];
    __shared__ float swt[TK];
    if (tid < TK) {
        sp[tid] = slot_inv[tok * TK + tid];
        swt[tid] = tkw[tok * TK + tid];
    }
    __syncthreads();
    int c = tid * 8;                 // 2048 / 256
    float* op = out + (size_t)tok * D + c;
    float acc[8];
    float4 o0 = *(float4*)op, o1 = *(float4*)(op + 4);
    acc[0] = o0.x; acc[1] = o0.y; acc[2] = o0.z; acc[3] = o0.w;
    acc[4] = o1.x; acc[5] = o1.y; acc[6] = o1.z; acc[7] = o1.w;
#pragma unroll
    for (int k = 0; k < TK; k++) {
        bf16x8 v = *(const bf16x8*)(outS + (size_t)sp[k] * D + c);
        float w = swt[k];
#pragma unroll
        for (int j = 0; j < 8; j++) acc[j] += w * (float)v[j];
    }
    o0 = make_float4(acc[0], acc[1], acc[2], acc[3]);
    o1 = make_float4(acc[4], acc[5], acc[6], acc[7]);
    *(float4*)op = o0;
    *(float4*)(op + 4) = o1;
}

// ------------------------------- launcher ---------------------------------

extern "C" void kernel_launch(void* const* d_in, const int* in_sizes, int n_in,
                              void* d_out, int out_size, void* d_ws, size_t ws_size,
                              hipStream_t stream) {
    const float* x  = (const float*)d_in[0];
    const float* gw = (const float*)d_in[1];
    const float* eb = (const float*)d_in[2];
    const float* gu = (const float*)d_in[3];
    const float* dn = (const float*)d_in[4];
    const float* sg = (const float*)d_in[5];
    const float* su = (const float*)d_in[6];
    const float* sd = (const float*)d_in[7];

    float* out        = (float*)d_out;
    float* out_idx    = out + (size_t)NTOK * D;
    float* out_scores = out_idx + (size_t)NTOK * TK;

    char* w = (char*)d_ws;
    auto alloc = [&](size_t bytes) {
        char* p = w;
        w += (bytes + 255) & ~(size_t)255;
        return p;
    };
    bf16_t* xb      = (bf16_t*)alloc((size_t)NTOK * D * 2);
    bf16_t* gut     = (bf16_t*)alloc((size_t)E * 2 * I * D * 2);   // [E][2I][D] interleaved
    bf16_t* dnt     = (bf16_t*)alloc((size_t)E * D * I * 2);       // [E][D][I]
    bf16_t* sh1t    = (bf16_t*)alloc((size_t)2 * I * D * 2);       // [2I][D] interleaved
    bf16_t* sdt     = (bf16_t*)alloc((size_t)D * I * 2);           // [D][I]
    bf16_t* inter   = (bf16_t*)alloc((size_t)NK * I * 2);
    bf16_t* inter_s = (bf16_t*)alloc((size_t)NTOK * I * 2);
    float*  tkw     = (float*)alloc((size_t)NK * 4);
    int*    tke     = (int*)alloc((size_t)NK * 4);
    int*    stok    = (int*)alloc((size_t)NK * 4);
    int*    sinv    = (int*)alloc((size_t)NK * 4);
    int*    counts  = (int*)alloc(E * 4);
    int*    offs    = (int*)alloc((E + 1) * 4);
    int*    curs    = (int*)alloc(E * 4);
    int4*   ttbl    = (int4*)alloc(MAX_TILES * 16);
    int*    ntl     = (int*)alloc(4);
    // outS[NK][D] bf16 (256MB) aliases gut (256MB): gut is dead after expert gemm1
    bf16_t* outS    = gut;

    if ((size_t)(w - (char*)d_ws) > ws_size) {
        k_sentinel<<<1, 64, 0, stream>>>(out);
        return;
    }

    k_zero_meta<<<1, 64, 0, stream>>>(counts, curs, ntl);
    k_convert_x<<<(NTOK * D / 8 + 255) / 256, 256, 0, stream>>>(x, xb, NTOK * D / 8);

    // weight reshapes
    k_transpose<1><<<dim3(2 * I / 32, D / 32, E), dim3(32, 8), 0, stream>>>(
        gu, gut, D, 2 * I, (size_t)D * 2 * I, (size_t)D * 2 * I);
    k_transpose<0><<<dim3(D / 32, I / 32, E), dim3(32, 8), 0, stream>>>(
        dn, dnt, I, D, (size_t)I * D, (size_t)I * D);
    k_transpose<2><<<dim3(I / 32, D / 32, 1), dim3(32, 8), 0, stream>>>(
        sg, sh1t, D, I, 0, 0);
    k_transpose<3><<<dim3(I / 32, D / 32, 1), dim3(32, 8), 0, stream>>>(
        su, sh1t, D, I, 0, 0);
    k_transpose<0><<<dim3(D / 32, I / 32, 1), dim3(32, 8), 0, stream>>>(
        sd, sdt, I, D, 0, 0);

    // routing
    k_router<<<NTOK, 256, 0, stream>>>(x, gw, eb, out_idx, out_scores, tkw, tke, counts);
    k_offsets<<<1, 64, 0, stream>>>(counts, offs, ttbl, ntl);
    k_scatter<<<NK / 256, 256, 0, stream>>>(tke, offs, curs, stok, sinv);

    constexpr size_t SMEM = 131072;
    // expert path (gemm1 must finish before outS overwrites gut)
    k_mm8<true, true, 0><<<dim3(8, MAX_TILES), 512, SMEM, stream>>>(
        xb, gut, D, (size_t)2 * I * D, stok, ttbl, ntl, inter, I);
    k_mm8<true, false, 1><<<dim3(8, MAX_TILES), 512, SMEM, stream>>>(
        inter, dnt, I, (size_t)D * I, stok, ttbl, ntl, outS, D);

    // shared path
    k_mm8<false, false, 0><<<dim3(8, NTOK / TM), 512, SMEM, stream>>>(
        xb, sh1t, D, 0, nullptr, nullptr, nullptr, inter_s, I);
    k_mm8<false, false, 2><<<dim3(8, NTOK / TM), 512, SMEM, stream>>>(
        inter_s, sdt, I, 0, nullptr, nullptr, nullptr, out, D);

    // combine
    k_finalize<<<NTOK, 256, 0, stream>>>(outS, sinv, tkw, out);
}

// Round 6
// 1857.429 us; speedup vs baseline: 1.8251x; 1.0173x over previous
//
#include <hip/hip_runtime.h>
#include <hip/hip_bf16.h>
#include <math.h>

// ---------------------------------------------------------------------------
// MoE block: router + grouped-expert SwiGLU + shared SwiGLU MLP.
// Round 6: + XCD-chunked block swizzle (T1) — each XCD gets 4 consecutive
// row-tiles x all 8 col-blocks, so A tiles are shared within one L2 instead
// of being fetched 8x across XCDs; B-first read order in P1/P5.
// ---------------------------------------------------------------------------

typedef __bf16 bf16_t;
typedef __bf16 bf16x8 __attribute__((ext_vector_type(8)));
typedef float  f32x4  __attribute__((ext_vector_type(4)));

constexpr int NTOK = 8192;          // B*S
constexpr int D    = 2048;
constexpr int E    = 32;
constexpr int I    = 1024;
constexpr int TK   = 8;             // TOP_K
constexpr int NK   = NTOK * TK;     // 65536 slots
constexpr int TM   = 256;           // GEMM row tile
constexpr int MAX_TILES = E + NK / TM;   // 288 worst-case row tiles (div by 8)
constexpr float RSCALE = 2.5f;

#define GL16(g, l) __builtin_amdgcn_global_load_lds( \
    (const __attribute__((address_space(1))) void*)(g), \
    (__attribute__((address_space(3))) void*)(l), 16, 0, 0)

// ------------------------------- utilities --------------------------------

__global__ __launch_bounds__(64) void k_zero_meta(int* counts, int* cursors, int* ntl) {
    int t = threadIdx.x;
    if (t < E) { counts[t] = 0; cursors[t] = 0; }
    if (t == 0) *ntl = 0;
}

__global__ __launch_bounds__(64) void k_sentinel(float* out) {
    if (threadIdx.x == 0) out[0] = 12345.0f;   // signals ws_size too small
}

// f32 -> bf16, 8 elems/thread
__global__ __launch_bounds__(256) void k_convert_x(const float* __restrict__ src,
                                                   bf16_t* __restrict__ dst, int n8) {
    int i = blockIdx.x * 256 + threadIdx.x;
    if (i >= n8) return;
    const float4* s = (const float4*)src;
    float4 a = s[(size_t)i * 2], b = s[(size_t)i * 2 + 1];
    bf16_t t[8] = {(bf16_t)a.x, (bf16_t)a.y, (bf16_t)a.z, (bf16_t)a.w,
                   (bf16_t)b.x, (bf16_t)b.y, (bf16_t)b.z, (bf16_t)b.w};
    *(uint4*)(dst + (size_t)i * 8) = *(const uint4*)t;
}

// batched transpose+convert: src [b][R][C] f32 -> dst [b][rc(C)][R] bf16
// MODE 0: rc=c | 1: gate/up interleave (c<I ? 2c : 2(c-I)+1) | 2: rc=2c | 3: rc=2c+1
template <int MODE>
__global__ __launch_bounds__(256) void k_transpose(const float* __restrict__ src,
                                                   bf16_t* __restrict__ dst,
                                                   int R, int C,
                                                   size_t srcMat, size_t dstMat) {
    __shared__ float t[32][33];
    int b = blockIdx.z;
    const float* s = src + (size_t)b * srcMat;
    bf16_t* d = dst + (size_t)b * dstMat;
    int c0 = blockIdx.x * 32, r0 = blockIdx.y * 32;
    int tx = threadIdx.x, ty = threadIdx.y;    // 32 x 8
#pragma unroll
    for (int yy = 0; yy < 4; yy++)
        t[ty + yy * 8][tx] = s[(size_t)(r0 + ty + yy * 8) * C + c0 + tx];
    __syncthreads();
#pragma unroll
    for (int yy = 0; yy < 4; yy++) {
        int c = c0 + ty + yy * 8;
        int rc = (MODE == 0) ? c
               : (MODE == 1) ? ((c < I) ? 2 * c : 2 * (c - I) + 1)
               : (MODE == 2) ? 2 * c : 2 * c + 1;
        d[(size_t)rc * R + r0 + tx] = (bf16_t)t[tx][ty + yy * 8];
    }
}

// ------------------------------- router -----------------------------------

__global__ __launch_bounds__(256) void k_router(const float* __restrict__ x,
                                                const float* __restrict__ gw,
                                                const float* __restrict__ eb,
                                                float* __restrict__ out_idx,
                                                float* __restrict__ out_scores,
                                                float* __restrict__ topk_w,
                                                int* __restrict__ tok_expert,
                                                int* __restrict__ counts) {
    int t = blockIdx.x;
    int tid = threadIdx.x;
    int e = tid & 31, part = tid >> 5;         // 8 parts x 256 d each
    const float* xr = x + (size_t)t * D;
    float partial = 0.f;
    int d0 = part * 256;
    for (int d = d0; d < d0 + 256; d++)
        partial += xr[d] * gw[(size_t)d * E + e];

    __shared__ float red[8][32];
    __shared__ float sc[32], sfr[32];
    red[part][e] = partial;
    __syncthreads();
    if (tid < 32) {
        float l = 0.f;
#pragma unroll
        for (int p = 0; p < 8; p++) l += red[p][tid];
        float s = 1.f / (1.f + expf(-l));
        sc[tid] = s;
        sfr[tid] = s + eb[tid];
        out_scores[(size_t)t * E + tid] = s;
    }
    __syncthreads();
    if (tid == 0) {
        float gs[8];
#pragma unroll
        for (int g = 0; g < 8; g++) {
            float m1 = -1e30f, m2 = -1e30f;
#pragma unroll
            for (int i = 0; i < 4; i++) {
                float v = sfr[g * 4 + i];
                if (v > m1) { m2 = m1; m1 = v; } else if (v > m2) m2 = v;
            }
            gs[g] = m1 + m2;
        }
        bool gsel[8] = {false, false, false, false, false, false, false, false};
        for (int it = 0; it < 4; it++) {
            int bi = -1; float bv = -1e30f;
            for (int g = 0; g < 8; g++)
                if (!gsel[g] && gs[g] > bv) { bv = gs[g]; bi = g; }
            gsel[bi] = true;
        }
        float masked[32];
        for (int i = 0; i < 32; i++) masked[i] = gsel[i >> 2] ? sfr[i] : -1e30f;
        int idx[TK]; float w[TK]; float wsum = 0.f;
        for (int k = 0; k < TK; k++) {
            int bi = 0; float bv = -1e30f;
            for (int i = 0; i < 32; i++)
                if (masked[i] > bv) { bv = masked[i]; bi = i; }
            masked[bi] = -1e30f;
            idx[k] = bi; w[k] = sc[bi]; wsum += w[k];
        }
        float inv = RSCALE / (wsum + 1e-20f);
        for (int k = 0; k < TK; k++) {
            out_idx[(size_t)t * TK + k] = (float)idx[k];
            topk_w[(size_t)t * TK + k] = w[k] * inv;
            tok_expert[(size_t)t * TK + k] = idx[k];
            atomicAdd(&counts[idx[k]], 1);
        }
    }
}

__global__ __launch_bounds__(64) void k_offsets(const int* __restrict__ counts,
                                                int* __restrict__ offs,
                                                int4* __restrict__ ttbl,
                                                int* __restrict__ ntl) {
    if (threadIdx.x != 0) return;
    int off = 0, nt = 0;
    for (int e = 0; e < E; e++) {
        offs[e] = off;
        int c = counts[e];
        for (int r = 0; r < c; r += TM) {
            ttbl[nt] = make_int4(off + r, min(TM, c - r), e, 0);
            nt++;
        }
        off += c;
    }
    offs[E] = off;
    *ntl = nt;
}

__global__ __launch_bounds__(256) void k_scatter(const int* __restrict__ tok_expert,
                                                 const int* __restrict__ offs,
                                                 int* __restrict__ cursors,
                                                 int* __restrict__ slot_token,
                                                 int* __restrict__ slot_inv) {
    int i = blockIdx.x * 256 + threadIdx.x;
    if (i >= NK) return;
    int e = tok_expert[i];
    int pos = offs[e] + atomicAdd(&cursors[e], 1);
    slot_token[pos] = i >> 3;   // TK = 8
    slot_inv[i] = pos;
}

// --------------------- 256x256 8-phase pipelined GEMM ----------------------
// 512 threads = 8 waves (2M x 4N); per-wave C = 128 rows x 64 cols.
// LDS 128 KiB: 2 buffers x (A[256][64] + B[256][64]) bf16, XOR-swizzled
// (16B chunk cb ^= row&7, applied on global source AND ds_read — rule #21).
//
// Stage plan, iteration j (tile t=2j in buf0, t+1 in buf1), 1 half/phase:
//   P1:A0(t+1)->buf1  P2:A1(t+1)->buf1  P3:B0(t+2)->buf0  P4:B1(t+2)->buf0
//   P5:A0(t+2)->buf0  P6:A1(t+2)->buf0  P7:B0(t+3)->buf1  P8:B1(t+3)->buf1
// vmcnt(4) at END of P4/P8 before the end-barrier: outstanding there = 12
// ops, draining to 4 completes exactly the next tile's 4 halves; the barrier
// publishes them to all waves.  Loop never drains vmcnt to 0 (T4).
//
// XCD swizzle (round-6): L = by*8+bx; XCD c = L&7; k = L>>3;
// tile-row ty = c*(gridY/8) + (k>>3), col-block tx = k&7.  All 8 col-blocks
// of a tile run concurrently on ONE XCD (A tile shared in that L2), with 4
// consecutive tiles resident (B panels shared across them).

#define SCB() __builtin_amdgcn_sched_barrier(0)

#define P_MID() do { __builtin_amdgcn_s_barrier(); SCB(); \
    __builtin_amdgcn_s_setprio(1); } while (0)

#define P_END() do { __builtin_amdgcn_s_setprio(0); \
    __builtin_amdgcn_s_barrier(); SCB(); } while (0)

#define P_END_VM4() do { __builtin_amdgcn_s_setprio(0); \
    asm volatile("s_waitcnt vmcnt(4)" ::: "memory"); \
    __builtin_amdgcn_s_barrier(); SCB(); } while (0)

#define STAGE_A(b, h, k0) do { \
    GL16(gA[h][0] + (k0), smb + (b) * 65536 + (h) * 16384 + w * 1024); \
    GL16(gA[h][1] + (k0), smb + (b) * 65536 + (h) * 16384 + 8192 + w * 1024); } while (0)

#define STAGE_B(b, h, k0) do { \
    GL16(gB[h][0] + (k0), smb + (b) * 65536 + 32768 + (h) * 16384 + w * 1024); \
    GL16(gB[h][1] + (k0), smb + (b) * 65536 + 32768 + (h) * 16384 + 8192 + w * 1024); } while (0)

#define LOAD_A(b, mh) do { _Pragma("unroll") for (int m_ = 0; m_ < 4; m_++) { \
    aF[m_][0] = *(const bf16x8*)(smb + (b) * 65536 + wm * 16384 + (mh) * 8192 + m_ * 2048 + lofs0); \
    aF[m_][1] = *(const bf16x8*)(smb + (b) * 65536 + wm * 16384 + (mh) * 8192 + m_ * 2048 + lofs1); } } while (0)

#define LOAD_B(b, nh) do { _Pragma("unroll") for (int n_ = 0; n_ < 2; n_++) { \
    bF[nh][n_][0] = *(const bf16x8*)(smb + (b) * 65536 + 32768 + wn * 8192 + (nh) * 4096 + n_ * 2048 + lofs0); \
    bF[nh][n_][1] = *(const bf16x8*)(smb + (b) * 65536 + 32768 + wn * 8192 + (nh) * 4096 + n_ * 2048 + lofs1); } } while (0)

#define MM(MH, NH) do { _Pragma("unroll") for (int m_ = 0; m_ < 4; m_++) \
    _Pragma("unroll") for (int n_ = 0; n_ < 2; n_++) { \
    acc[(MH) * 4 + m_][(NH) * 2 + n_] = __builtin_amdgcn_mfma_f32_16x16x32_bf16( \
        aF[m_][0], bF[NH][n_][0], acc[(MH) * 4 + m_][(NH) * 2 + n_], 0, 0, 0); \
    acc[(MH) * 4 + m_][(NH) * 2 + n_] = __builtin_amdgcn_mfma_f32_16x16x32_bf16( \
        aF[m_][1], bF[NH][n_][1], acc[(MH) * 4 + m_][(NH) * 2 + n_], 0, 0, 0); } } while (0)

template <bool EXPERT, bool GATHER, int EPI>
__global__ __launch_bounds__(512, 2) void k_mm8(const bf16_t* __restrict__ A,
                                                const bf16_t* __restrict__ Bt,
                                                int K, size_t estride,
                                                const int* __restrict__ slot_token,
                                                const int4* __restrict__ ttbl,
                                                const int* __restrict__ ntl,
                                                void* __restrict__ C, int ldc) {
    // XCD-chunked swizzle (grid.y divisible by 8)
    int L = (int)blockIdx.y * 8 + (int)blockIdx.x;
    int xcd = L & 7, k = L >> 3;
    int per = (int)gridDim.y >> 3;
    int ty = xcd * per + (k >> 3);
    int tx = k & 7;

    int base_slot, rows, e;
    if (EXPERT) {
        if (ty >= *ntl) return;
        int4 tt = ttbl[ty];
        base_slot = tt.x; rows = tt.y; e = tt.z;
    } else {
        base_slot = ty * TM; rows = TM; e = 0;
    }
    int c0 = tx * 256;
    const bf16_t* Bw = Bt + (size_t)e * estride + (size_t)c0 * K;

    extern __shared__ char smb[];   // 128 KiB: [2][A 32K | B 32K]

    int tid = threadIdx.x, lane = tid & 63, w = tid >> 6;
    int wm = w >> 2, wn = w & 3;
    int lr = lane & 15, hi = lane >> 4;
    int rx = lr & 7;
    // swizzled ds_read lane offsets (16B chunk cb in [0,8), cb ^= row&7)
    int lofs0 = lr * 128 + ((hi ^ rx) << 4);
    int lofs1 = lr * 128 + (((4 + hi) ^ rx) << 4);

    // staging: row = h*128 + rnd*64 + tid/8; global chunk = (tid&7) ^ (row&7)
    int srow = tid >> 3;
    int cbg = (tid & 7) ^ (srow & 7);
    const bf16_t* gA[2][2]; const bf16_t* gB[2][2];
#pragma unroll
    for (int h = 0; h < 2; h++)
#pragma unroll
        for (int rnd = 0; rnd < 2; rnd++) {
            int r = h * 128 + rnd * 64 + srow;
            int ar = min(r, rows - 1);
            int tok = GATHER ? slot_token[base_slot + ar] : (base_slot + ar);
            gA[h][rnd] = A + (size_t)tok * K + cbg * 8;
            gB[h][rnd] = Bw + (size_t)r * K + cbg * 8;
        }

    f32x4 acc[8][4] = {};
    bf16x8 aF[4][2], bF[2][2][2];

    // prologue: buf0 <- tile0 (8 ops), buf1 <- tile1 B (4 ops); drain to 4;
    // barrier publishes tile0 to all waves before P1's ds_reads.
    STAGE_B(0, 0, 0); STAGE_B(0, 1, 0);
    STAGE_A(0, 0, 0); STAGE_A(0, 1, 0);
    STAGE_B(1, 0, 64); STAGE_B(1, 1, 64);
    asm volatile("s_waitcnt vmcnt(4)" ::: "memory");
    __builtin_amdgcn_s_barrier();
    SCB();

    int nt = K >> 6;                 // K/64, even (16 or 32)
    for (int kt = 0; kt < nt; kt += 2) {
        int k1 = (kt + 1) << 6;
        int k2 = (kt + 2 < nt) ? (kt + 2) << 6 : 0;   // wrapped, never read
        int k3 = (kt + 3 < nt) ? (kt + 3) << 6 : 0;
        // P1  (B reads first: earlier MFMA start under counted lgkmcnt)
        LOAD_B(0, 0); LOAD_A(0, 0);
        STAGE_A(1, 0, k1);
        P_MID(); MM(0, 0); P_END();
        // P2
        LOAD_B(0, 1);
        STAGE_A(1, 1, k1);
        P_MID(); MM(0, 1); P_END();
        // P3
        LOAD_A(0, 1);
        STAGE_B(0, 0, k2);
        P_MID(); MM(1, 0); P_END();
        // P4
        STAGE_B(0, 1, k2);
        P_MID(); MM(1, 1); P_END_VM4();
        // P5
        LOAD_B(1, 0); LOAD_A(1, 0);
        STAGE_A(0, 0, k2);
        P_MID(); MM(0, 0); P_END();
        // P6
        LOAD_B(1, 1);
        STAGE_A(0, 1, k2);
        P_MID(); MM(0, 1); P_END();
        // P7
        LOAD_A(1, 1);
        STAGE_B(1, 0, k3);
        P_MID(); MM(1, 0); P_END();
        // P8
        STAGE_B(1, 1, k3);
        P_MID(); MM(1, 1); P_END_VM4();
    }

    // epilogue: C row r = wm*128 + mi*16 + hi*4 + j, col = c0 + wn*64 + f*16 + lr
#pragma unroll
    for (int mi = 0; mi < 8; mi++) {
#pragma unroll
        for (int j = 0; j < 4; j++) {
            int r = wm * 128 + mi * 16 + hi * 4 + j;
            bool valid = !EXPERT || (r < rows);
            size_t orow = (size_t)base_slot + r;
#pragma unroll
            for (int f = 0; f < 4; f++) {
                float v = acc[mi][f][j];
                int c = c0 + wn * 64 + f * 16 + lr;
                if (EPI == 0) {
                    float o = __shfl_xor(v, 1);
                    float g = (lane & 1) ? o : v;
                    float u = (lane & 1) ? v : o;
                    float sv = g / (1.f + __expf(-g)) * u;
                    if (valid && !(lane & 1))
                        ((bf16_t*)C)[orow * ldc + (c >> 1)] = (bf16_t)sv;
                } else if (EPI == 1) {
                    float o = __shfl_xor(v, 1);
                    if (valid && !(lane & 1)) {
                        bf16_t pr[2] = {(bf16_t)v, (bf16_t)o};
                        *(unsigned int*)((bf16_t*)C + orow * ldc + c) = *(unsigned int*)pr;
                    }
                } else {
                    if (valid) ((float*)C)[orow * ldc + c] = v;
                }
            }
        }
    }
}

// ------------------------------- finalize ----------------------------------
// out[tok][d] += sum_k w_k * outS[pos(tok,k)][d]   (out already = shared MLP)

__global__ __launch_bounds__(256) void k_finalize(const bf16_t* __restrict__ outS,
                                                  const int* __restrict__ slot_inv,
                                                  const float* __restrict__ tkw,
                                                  float* __restrict__ out) {
    int tok = blockIdx.x, tid = threadIdx.x;
    __shared__ int sp[TK];
    __shared__ float swt[TK];
    if (tid < TK) {
        sp[tid] = slot_inv[tok * TK + tid];
        swt[tid] = tkw[tok * TK + tid];
    }
    __syncthreads();
    int c = tid * 8;                 // 2048 / 256
    float* op = out + (size_t)tok * D + c;
    float acc[8];
    float4 o0 = *(float4*)op, o1 = *(float4*)(op + 4);
    acc[0] = o0.x; acc[1] = o0.y; acc[2] = o0.z; acc[3] = o0.w;
    acc[4] = o1.x; acc[5] = o1.y; acc[6] = o1.z; acc[7] = o1.w;
#pragma unroll
    for (int k = 0; k < TK; k++) {
        bf16x8 v = *(const bf16x8*)(outS + (size_t)sp[k] * D + c);
        float w = swt[k];
#pragma unroll
        for (int j = 0; j < 8; j++) acc[j] += w * (float)v[j];
    }
    o0 = make_float4(acc[0], acc[1], acc[2], acc[3]);
    o1 = make_float4(acc[4], acc[5], acc[6], acc[7]);
    *(float4*)op = o0;
    *(float4*)(op + 4) = o1;
}

// ------------------------------- launcher ---------------------------------

extern "C" void kernel_launch(void* const* d_in, const int* in_sizes, int n_in,
                              void* d_out, int out_size, void* d_ws, size_t ws_size,
                              hipStream_t stream) {
    const float* x  = (const float*)d_in[0];
    const float* gw = (const float*)d_in[1];
    const float* eb = (const float*)d_in[2];
    const float* gu = (const float*)d_in[3];
    const float* dn = (const float*)d_in[4];
    const float* sg = (const float*)d_in[5];
    const float* su = (const float*)d_in[6];
    const float* sd = (const float*)d_in[7];

    float* out        = (float*)d_out;
    float* out_idx    = out + (size_t)NTOK * D;
    float* out_scores = out_idx + (size_t)NTOK * TK;

    char* w = (char*)d_ws;
    auto alloc = [&](size_t bytes) {
        char* p = w;
        w += (bytes + 255) & ~(size_t)255;
        return p;
    };
    bf16_t* xb      = (bf16_t*)alloc((size_t)NTOK * D * 2);
    bf16_t* gut     = (bf16_t*)alloc((size_t)E * 2 * I * D * 2);   // [E][2I][D] interleaved
    bf16_t* dnt     = (bf16_t*)alloc((size_t)E * D * I * 2);       // [E][D][I]
    bf16_t* sh1t    = (bf16_t*)alloc((size_t)2 * I * D * 2);       // [2I][D] interleaved
    bf16_t* sdt     = (bf16_t*)alloc((size_t)D * I * 2);           // [D][I]
    bf16_t* inter   = (bf16_t*)alloc((size_t)NK * I * 2);
    bf16_t* inter_s = (bf16_t*)alloc((size_t)NTOK * I * 2);
    float*  tkw     = (float*)alloc((size_t)NK * 4);
    int*    tke     = (int*)alloc((size_t)NK * 4);
    int*    stok    = (int*)alloc((size_t)NK * 4);
    int*    sinv    = (int*)alloc((size_t)NK * 4);
    int*    counts  = (int*)alloc(E * 4);
    int*    offs    = (int*)alloc((E + 1) * 4);
    int*    curs    = (int*)alloc(E * 4);
    int4*   ttbl    = (int4*)alloc(MAX_TILES * 16);
    int*    ntl     = (int*)alloc(4);
    // outS[NK][D] bf16 (256MB) aliases gut (256MB): gut is dead after expert gemm1
    bf16_t* outS    = gut;

    if ((size_t)(w - (char*)d_ws) > ws_size) {
        k_sentinel<<<1, 64, 0, stream>>>(out);
        return;
    }

    k_zero_meta<<<1, 64, 0, stream>>>(counts, curs, ntl);
    k_convert_x<<<(NTOK * D / 8 + 255) / 256, 256, 0, stream>>>(x, xb, NTOK * D / 8);

    // weight reshapes
    k_transpose<1><<<dim3(2 * I / 32, D / 32, E), dim3(32, 8), 0, stream>>>(
        gu, gut, D, 2 * I, (size_t)D * 2 * I, (size_t)D * 2 * I);
    k_transpose<0><<<dim3(D / 32, I / 32, E), dim3(32, 8), 0, stream>>>(
        dn, dnt, I, D, (size_t)I * D, (size_t)I * D);
    k_transpose<2><<<dim3(I / 32, D / 32, 1), dim3(32, 8), 0, stream>>>(
        sg, sh1t, D, I, 0, 0);
    k_transpose<3><<<dim3(I / 32, D / 32, 1), dim3(32, 8), 0, stream>>>(
        su, sh1t, D, I, 0, 0);
    k_transpose<0><<<dim3(D / 32, I / 32, 1), dim3(32, 8), 0, stream>>>(
        sd, sdt, I, D, 0, 0);

    // routing
    k_router<<<NTOK, 256, 0, stream>>>(x, gw, eb, out_idx, out_scores, tkw, tke, counts);
    k_offsets<<<1, 64, 0, stream>>>(counts, offs, ttbl, ntl);
    k_scatter<<<NK / 256, 256, 0, stream>>>(tke, offs, curs, stok, sinv);

    constexpr size_t SMEM = 131072;
    // expert path (gemm1 must finish before outS overwrites gut)
    k_mm8<true, true, 0><<<dim3(8, MAX_TILES), 512, SMEM, stream>>>(
        xb, gut, D, (size_t)2 * I * D, stok, ttbl, ntl, inter, I);
    k_mm8<true, false, 1><<<dim3(8, MAX_TILES), 512, SMEM, stream>>>(
        inter, dnt, I, (size_t)D * I, stok, ttbl, ntl, outS, D);

    // shared path
    k_mm8<false, false, 0><<<dim3(8, NTOK / TM), 512, SMEM, stream>>>(
        xb, sh1t, D, 0, nullptr, nullptr, nullptr, inter_s, I);
    k_mm8<false, false, 2><<<dim3(8, NTOK / TM), 512, SMEM, stream>>>(
        inter_s, sdt, I, 0, nullptr, nullptr, nullptr, out, D);

    // combine
    k_finalize<<<NTOK, 256, 0, stream>>>(outS, sinv, tkw, out);
}

// Round 7
// 1819.424 us; speedup vs baseline: 1.8632x; 1.0209x over previous
//
#include <hip/hip_runtime.h>
#include <hip/hip_bf16.h>
#include <math.h>

// ---------------------------------------------------------------------------
// MoE block: router + grouped-expert SwiGLU + shared SwiGLU MLP.
// Round 7: register-prefetch-1 pipeline — phase p issues ds_reads for phase
// p+1's MFMA, so LDS drain overlaps the MFMA cluster instead of preceding it.
// Single aF set (A-halves die after 2 phases), b0/b1 pair, 1 barrier/phase,
// vmcnt(4) every phase end (ops@q published at (q+2)-end; all deadlines and
// WAR gaps >= 2 phases verified in comments below).
// ---------------------------------------------------------------------------

typedef __bf16 bf16_t;
typedef __bf16 bf16x8 __attribute__((ext_vector_type(8)));
typedef float  f32x4  __attribute__((ext_vector_type(4)));

constexpr int NTOK = 8192;          // B*S
constexpr int D    = 2048;
constexpr int E    = 32;
constexpr int I    = 1024;
constexpr int TK   = 8;             // TOP_K
constexpr int NK   = NTOK * TK;     // 65536 slots
constexpr int TM   = 256;           // GEMM row tile
constexpr int MAX_TILES = E + NK / TM;   // 288 worst-case row tiles (div by 8)
constexpr float RSCALE = 2.5f;

#define GL16(g, l) __builtin_amdgcn_global_load_lds( \
    (const __attribute__((address_space(1))) void*)(g), \
    (__attribute__((address_space(3))) void*)(l), 16, 0, 0)

// ------------------------------- utilities --------------------------------

__global__ __launch_bounds__(64) void k_zero_meta(int* counts, int* cursors, int* ntl) {
    int t = threadIdx.x;
    if (t < E) { counts[t] = 0; cursors[t] = 0; }
    if (t == 0) *ntl = 0;
}

__global__ __launch_bounds__(64) void k_sentinel(float* out) {
    if (threadIdx.x == 0) out[0] = 12345.0f;   // signals ws_size too small
}

// f32 -> bf16, 8 elems/thread
__global__ __launch_bounds__(256) void k_convert_x(const float* __restrict__ src,
                                                   bf16_t* __restrict__ dst, int n8) {
    int i = blockIdx.x * 256 + threadIdx.x;
    if (i >= n8) return;
    const float4* s = (const float4*)src;
    float4 a = s[(size_t)i * 2], b = s[(size_t)i * 2 + 1];
    bf16_t t[8] = {(bf16_t)a.x, (bf16_t)a.y, (bf16_t)a.z, (bf16_t)a.w,
                   (bf16_t)b.x, (bf16_t)b.y, (bf16_t)b.z, (bf16_t)b.w};
    *(uint4*)(dst + (size_t)i * 8) = *(const uint4*)t;
}

// batched transpose+convert: src [b][R][C] f32 -> dst [b][rc(C)][R] bf16
// MODE 0: rc=c | 1: gate/up interleave (c<I ? 2c : 2(c-I)+1) | 2: rc=2c | 3: rc=2c+1
template <int MODE>
__global__ __launch_bounds__(256) void k_transpose(const float* __restrict__ src,
                                                   bf16_t* __restrict__ dst,
                                                   int R, int C,
                                                   size_t srcMat, size_t dstMat) {
    __shared__ float t[32][33];
    int b = blockIdx.z;
    const float* s = src + (size_t)b * srcMat;
    bf16_t* d = dst + (size_t)b * dstMat;
    int c0 = blockIdx.x * 32, r0 = blockIdx.y * 32;
    int tx = threadIdx.x, ty = threadIdx.y;    // 32 x 8
#pragma unroll
    for (int yy = 0; yy < 4; yy++)
        t[ty + yy * 8][tx] = s[(size_t)(r0 + ty + yy * 8) * C + c0 + tx];
    __syncthreads();
#pragma unroll
    for (int yy = 0; yy < 4; yy++) {
        int c = c0 + ty + yy * 8;
        int rc = (MODE == 0) ? c
               : (MODE == 1) ? ((c < I) ? 2 * c : 2 * (c - I) + 1)
               : (MODE == 2) ? 2 * c : 2 * c + 1;
        d[(size_t)rc * R + r0 + tx] = (bf16_t)t[tx][ty + yy * 8];
    }
}

// ------------------------------- router -----------------------------------

__global__ __launch_bounds__(256) void k_router(const float* __restrict__ x,
                                                const float* __restrict__ gw,
                                                const float* __restrict__ eb,
                                                float* __restrict__ out_idx,
                                                float* __restrict__ out_scores,
                                                float* __restrict__ topk_w,
                                                int* __restrict__ tok_expert,
                                                int* __restrict__ counts) {
    int t = blockIdx.x;
    int tid = threadIdx.x;
    int e = tid & 31, part = tid >> 5;         // 8 parts x 256 d each
    const float* xr = x + (size_t)t * D;
    float partial = 0.f;
    int d0 = part * 256;
    for (int d = d0; d < d0 + 256; d++)
        partial += xr[d] * gw[(size_t)d * E + e];

    __shared__ float red[8][32];
    __shared__ float sc[32], sfr[32];
    red[part][e] = partial;
    __syncthreads();
    if (tid < 32) {
        float l = 0.f;
#pragma unroll
        for (int p = 0; p < 8; p++) l += red[p][tid];
        float s = 1.f / (1.f + expf(-l));
        sc[tid] = s;
        sfr[tid] = s + eb[tid];
        out_scores[(size_t)t * E + tid] = s;
    }
    __syncthreads();
    if (tid == 0) {
        float gs[8];
#pragma unroll
        for (int g = 0; g < 8; g++) {
            float m1 = -1e30f, m2 = -1e30f;
#pragma unroll
            for (int i = 0; i < 4; i++) {
                float v = sfr[g * 4 + i];
                if (v > m1) { m2 = m1; m1 = v; } else if (v > m2) m2 = v;
            }
            gs[g] = m1 + m2;
        }
        bool gsel[8] = {false, false, false, false, false, false, false, false};
        for (int it = 0; it < 4; it++) {
            int bi = -1; float bv = -1e30f;
            for (int g = 0; g < 8; g++)
                if (!gsel[g] && gs[g] > bv) { bv = gs[g]; bi = g; }
            gsel[bi] = true;
        }
        float masked[32];
        for (int i = 0; i < 32; i++) masked[i] = gsel[i >> 2] ? sfr[i] : -1e30f;
        int idx[TK]; float w[TK]; float wsum = 0.f;
        for (int k = 0; k < TK; k++) {
            int bi = 0; float bv = -1e30f;
            for (int i = 0; i < 32; i++)
                if (masked[i] > bv) { bv = masked[i]; bi = i; }
            masked[bi] = -1e30f;
            idx[k] = bi; w[k] = sc[bi]; wsum += w[k];
        }
        float inv = RSCALE / (wsum + 1e-20f);
        for (int k = 0; k < TK; k++) {
            out_idx[(size_t)t * TK + k] = (float)idx[k];
            topk_w[(size_t)t * TK + k] = w[k] * inv;
            tok_expert[(size_t)t * TK + k] = idx[k];
            atomicAdd(&counts[idx[k]], 1);
        }
    }
}

__global__ __launch_bounds__(64) void k_offsets(const int* __restrict__ counts,
                                                int* __restrict__ offs,
                                                int4* __restrict__ ttbl,
                                                int* __restrict__ ntl) {
    if (threadIdx.x != 0) return;
    int off = 0, nt = 0;
    for (int e = 0; e < E; e++) {
        offs[e] = off;
        int c = counts[e];
        for (int r = 0; r < c; r += TM) {
            ttbl[nt] = make_int4(off + r, min(TM, c - r), e, 0);
            nt++;
        }
        off += c;
    }
    offs[E] = off;
    *ntl = nt;
}

__global__ __launch_bounds__(256) void k_scatter(const int* __restrict__ tok_expert,
                                                 const int* __restrict__ offs,
                                                 int* __restrict__ cursors,
                                                 int* __restrict__ slot_token,
                                                 int* __restrict__ slot_inv) {
    int i = blockIdx.x * 256 + threadIdx.x;
    if (i >= NK) return;
    int e = tok_expert[i];
    int pos = offs[e] + atomicAdd(&cursors[e], 1);
    slot_token[pos] = i >> 3;   // TK = 8
    slot_inv[i] = pos;
}

// --------------------- 256x256 8-phase pipelined GEMM ----------------------
// 512 threads = 8 waves (2M x 4N); per-wave C = 128 rows x 64 cols.
// LDS 128 KiB: 2 buffers x (A[256][64] + B[256][64]) bf16, XOR-swizzled.
//
// REGISTER PREFETCH-1: reads issued in phase p feed the MFMA of p+1:
//   P8: aF<-b0f.mh0 + b0<-b0f.nh0 (12)   [b0f = buf0 NEXT tile]
//   P1: b1<-b0f.nh1 (4)   P2: aF<-b0f.mh1 (8)  P3: -
//   P4: aF<-b1f.mh0 + b0<-b1f.nh0 (12)   P5: b1<-b1f.nh1 (4)
//   P6: aF<-b1f.mh1 (8)   P7: -
// MFMA@p waits only on reads@p-1 (counted lgkm, compiler); reads@p drain
// under MFMA@p. aF single set: each A-half used 2 consecutive phases then
// reloaded (loads placed AFTER the MFMA in P2/P4/P6/P8 to respect WAR).
//
// STAGES: 2 GL16/phase, unit = matching read-half granularity:
//   P1:A1(rnd1,t1)  P2:A0(rnd0,t0+2)  P3:B0(h0,t0+2)  P4:B0(h1,t0+2)
//   P5:A0(rnd1,t0+2) P6:A1(rnd0,t1+2) P7:B1(h0,t1+2)  P8:B1(h1,t1+2)
// vmcnt(4) at EVERY phase end => ops@q published at (q+2)-end. All read
// deadlines hold with >=1 phase slack; every stage lands >=2 phases after
// its region's last read-issue (those reads are MFMA operands of the
// intervening phase, drained before its end-barrier => hard WAR-safe).

#define SCB() __builtin_amdgcn_sched_barrier(0)

#define PEND() do { asm volatile("s_waitcnt vmcnt(4)" ::: "memory"); \
    __builtin_amdgcn_s_barrier(); SCB(); } while (0)

// A stage unit (b, rnd): rows rnd*64..+63 and 128+rnd*64..+63
#define SA2(b, rnd, k0) do { \
    GL16(gA[0][rnd] + (k0), smb + (b) * 65536 + (rnd) * 8192 + w * 1024); \
    GL16(gA[1][rnd] + (k0), smb + (b) * 65536 + 16384 + (rnd) * 8192 + w * 1024); } while (0)

// B stage unit (b, h): cols h*128..+127
#define SB(b, h, k0) do { \
    GL16(gB[h][0] + (k0), smb + (b) * 65536 + 32768 + (h) * 16384 + w * 1024); \
    GL16(gB[h][1] + (k0), smb + (b) * 65536 + 32768 + (h) * 16384 + 8192 + w * 1024); } while (0)

#define LDA(b, mh) do { _Pragma("unroll") for (int m_ = 0; m_ < 4; m_++) { \
    aF[m_][0] = *(const bf16x8*)(smb + (b) * 65536 + wm * 16384 + (mh) * 8192 + m_ * 2048 + lofs0); \
    aF[m_][1] = *(const bf16x8*)(smb + (b) * 65536 + wm * 16384 + (mh) * 8192 + m_ * 2048 + lofs1); } } while (0)

#define LDB(dst, b, nh) do { _Pragma("unroll") for (int n_ = 0; n_ < 2; n_++) { \
    dst[n_][0] = *(const bf16x8*)(smb + (b) * 65536 + 32768 + wn * 8192 + (nh) * 4096 + n_ * 2048 + lofs0); \
    dst[n_][1] = *(const bf16x8*)(smb + (b) * 65536 + 32768 + wn * 8192 + (nh) * 4096 + n_ * 2048 + lofs1); } } while (0)

#define MMA(bv, MH, NH) do { \
    __builtin_amdgcn_s_setprio(1); \
    _Pragma("unroll") for (int m_ = 0; m_ < 4; m_++) \
    _Pragma("unroll") for (int n_ = 0; n_ < 2; n_++) { \
    acc[(MH) * 4 + m_][(NH) * 2 + n_] = __builtin_amdgcn_mfma_f32_16x16x32_bf16( \
        aF[m_][0], bv[n_][0], acc[(MH) * 4 + m_][(NH) * 2 + n_], 0, 0, 0); \
    acc[(MH) * 4 + m_][(NH) * 2 + n_] = __builtin_amdgcn_mfma_f32_16x16x32_bf16( \
        aF[m_][1], bv[n_][1], acc[(MH) * 4 + m_][(NH) * 2 + n_], 0, 0, 0); } \
    __builtin_amdgcn_s_setprio(0); } while (0)

template <bool EXPERT, bool GATHER, int EPI>
__global__ __launch_bounds__(512, 2) void k_mm8(const bf16_t* __restrict__ A,
                                                const bf16_t* __restrict__ Bt,
                                                int K, size_t estride,
                                                const int* __restrict__ slot_token,
                                                const int4* __restrict__ ttbl,
                                                const int* __restrict__ ntl,
                                                void* __restrict__ C, int ldc) {
    // XCD-chunked swizzle (grid.y divisible by 8)
    int L = (int)blockIdx.y * 8 + (int)blockIdx.x;
    int xcd = L & 7, k = L >> 3;
    int per = (int)gridDim.y >> 3;
    int ty = xcd * per + (k >> 3);
    int tx = k & 7;

    int base_slot, rows, e;
    if (EXPERT) {
        if (ty >= *ntl) return;
        int4 tt = ttbl[ty];
        base_slot = tt.x; rows = tt.y; e = tt.z;
    } else {
        base_slot = ty * TM; rows = TM; e = 0;
    }
    int c0 = tx * 256;
    const bf16_t* Bw = Bt + (size_t)e * estride + (size_t)c0 * K;

    extern __shared__ char smb[];   // 128 KiB: [2][A 32K | B 32K]

    int tid = threadIdx.x, lane = tid & 63, w = tid >> 6;
    int wm = w >> 2, wn = w & 3;
    int lr = lane & 15, hi = lane >> 4;
    int rx = lr & 7;
    // swizzled ds_read lane offsets (16B chunk cb in [0,8), cb ^= row&7)
    int lofs0 = lr * 128 + ((hi ^ rx) << 4);
    int lofs1 = lr * 128 + (((4 + hi) ^ rx) << 4);

    // staging: row = h*128 + rnd*64 + tid/8; global chunk = (tid&7) ^ (row&7)
    int srow = tid >> 3;
    int cbg = (tid & 7) ^ (srow & 7);
    const bf16_t* gA[2][2]; const bf16_t* gB[2][2];
#pragma unroll
    for (int h = 0; h < 2; h++)
#pragma unroll
        for (int rnd = 0; rnd < 2; rnd++) {
            int r = h * 128 + rnd * 64 + srow;
            int ar = min(r, rows - 1);
            int tok = GATHER ? slot_token[base_slot + ar] : (base_slot + ar);
            gA[h][rnd] = A + (size_t)tok * K + cbg * 8;
            gB[h][rnd] = Bw + (size_t)r * K + cbg * 8;
        }

    f32x4 acc[8][4] = {};
    bf16x8 aF[4][2], b0[2][2], b1[2][2];

    // prologue: buf0 full (t0=0), buf1 all but A.rnd1 (t1=1; A.rnd1 staged at
    // P1 of the first iteration). Full drain + barrier, then pre-reads for P1.
    SA2(0, 0, 0); SA2(0, 1, 0);
    SB(0, 0, 0); SB(0, 1, 0);
    SA2(1, 0, 64);
    SB(1, 0, 64); SB(1, 1, 64);
    asm volatile("s_waitcnt vmcnt(0)" ::: "memory");
    __builtin_amdgcn_s_barrier();
    SCB();
    LDA(0, 0); LDB(b0, 0, 0);

    int nt = K >> 6;                 // K/64, even (16 or 32)
    for (int kt = 0; kt < nt; kt += 2) {
        int k1 = (kt + 1) << 6;
        int k2 = (kt + 2 < nt) ? (kt + 2) << 6 : 0;   // wrapped, never read
        int k3 = (kt + 3 < nt) ? (kt + 3) << 6 : 0;
        // P1: MFMA(mh0,nh0 buf0) | reads b1 | stage buf1.A.rnd1[t1]
        LDB(b1, 0, 1);
        MMA(b0, 0, 0);
        SA2(1, 1, k1);
        PEND();
        // P2: MFMA(mh0,nh1) | reads aF<-buf0.mh1 (after MFMA: WAR) | stage A0.rnd0[t0+2]
        MMA(b1, 0, 1);
        LDA(0, 1);
        SA2(0, 0, k2);
        PEND();
        // P3: MFMA(mh1,nh0) | stage B0.h0[t0+2]
        MMA(b0, 1, 0);
        SB(0, 0, k2);
        PEND();
        // P4: MFMA(mh1,nh1) | reads aF<-buf1.mh0, b0<-buf1.nh0 | stage B0.h1[t0+2]
        MMA(b1, 1, 1);
        LDA(1, 0); LDB(b0, 1, 0);
        SB(0, 1, k2);
        PEND();
        // P5: MFMA(mh0,nh0 buf1) | reads b1<-buf1.nh1 | stage A0.rnd1[t0+2]
        LDB(b1, 1, 1);
        MMA(b0, 0, 0);
        SA2(0, 1, k2);
        PEND();
        // P6: MFMA(mh0,nh1) | reads aF<-buf1.mh1 | stage A1.rnd0[t1+2]
        MMA(b1, 0, 1);
        LDA(1, 1);
        SA2(1, 0, k3);
        PEND();
        // P7: MFMA(mh1,nh0) | stage B1.h0[t1+2]
        MMA(b0, 1, 0);
        SB(1, 0, k3);
        PEND();
        // P8: MFMA(mh1,nh1) | reads aF,b0 <- buf0[t0+2] | stage B1.h1[t1+2]
        MMA(b1, 1, 1);
        LDA(0, 0); LDB(b0, 0, 0);
        SB(1, 1, k3);
        PEND();
    }

    // epilogue: C row r = wm*128 + mi*16 + hi*4 + j, col = c0 + wn*64 + f*16 + lr
#pragma unroll
    for (int mi = 0; mi < 8; mi++) {
#pragma unroll
        for (int j = 0; j < 4; j++) {
            int r = wm * 128 + mi * 16 + hi * 4 + j;
            bool valid = !EXPERT || (r < rows);
            size_t orow = (size_t)base_slot + r;
#pragma unroll
            for (int f = 0; f < 4; f++) {
                float v = acc[mi][f][j];
                int c = c0 + wn * 64 + f * 16 + lr;
                if (EPI == 0) {
                    float o = __shfl_xor(v, 1);
                    float g = (lane & 1) ? o : v;
                    float u = (lane & 1) ? v : o;
                    float sv = g / (1.f + __expf(-g)) * u;
                    if (valid && !(lane & 1))
                        ((bf16_t*)C)[orow * ldc + (c >> 1)] = (bf16_t)sv;
                } else if (EPI == 1) {
                    float o = __shfl_xor(v, 1);
                    if (valid && !(lane & 1)) {
                        bf16_t pr[2] = {(bf16_t)v, (bf16_t)o};
                        *(unsigned int*)((bf16_t*)C + orow * ldc + c) = *(unsigned int*)pr;
                    }
                } else {
                    if (valid) ((float*)C)[orow * ldc + c] = v;
                }
            }
        }
    }
}

// ------------------------------- finalize ----------------------------------
// out[tok][d] += sum_k w_k * outS[pos(tok,k)][d]   (out already = shared MLP)

__global__ __launch_bounds__(256) void k_finalize(const bf16_t* __restrict__ outS,
                                                  const int* __restrict__ slot_inv,
                                                  const float* __restrict__ tkw,
                                                  float* __restrict__ out) {
    int tok = blockIdx.x, tid = threadIdx.x;
    __shared__ int sp[TK];
    __shared__ float swt[TK];
    if (tid < TK) {
        sp[tid] = slot_inv[tok * TK + tid];
        swt[tid] = tkw[tok * TK + tid];
    }
    __syncthreads();
    int c = tid * 8;                 // 2048 / 256
    float* op = out + (size_t)tok * D + c;
    float acc[8];
    float4 o0 = *(float4*)op, o1 = *(float4*)(op + 4);
    acc[0] = o0.x; acc[1] = o0.y; acc[2] = o0.z; acc[3] = o0.w;
    acc[4] = o1.x; acc[5] = o1.y; acc[6] = o1.z; acc[7] = o1.w;
#pragma unroll
    for (int k = 0; k < TK; k++) {
        bf16x8 v = *(const bf16x8*)(outS + (size_t)sp[k] * D + c);
        float w = swt[k];
#pragma unroll
        for (int j = 0; j < 8; j++) acc[j] += w * (float)v[j];
    }
    o0 = make_float4(acc[0], acc[1], acc[2], acc[3]);
    o1 = make_float4(acc[4], acc[5], acc[6], acc[7]);
    *(float4*)op = o0;
    *(float4*)(op + 4) = o1;
}

// ------------------------------- launcher ---------------------------------

extern "C" void kernel_launch(void* const* d_in, const int* in_sizes, int n_in,
                              void* d_out, int out_size, void* d_ws, size_t ws_size,
                              hipStream_t stream) {
    const float* x  = (const float*)d_in[0];
    const float* gw = (const float*)d_in[1];
    const float* eb = (const float*)d_in[2];
    const float* gu = (const float*)d_in[3];
    const float* dn = (const float*)d_in[4];
    const float* sg = (const float*)d_in[5];
    const float* su = (const float*)d_in[6];
    const float* sd = (const float*)d_in[7];

    float* out        = (float*)d_out;
    float* out_idx    = out + (size_t)NTOK * D;
    float* out_scores = out_idx + (size_t)NTOK * TK;

    char* w = (char*)d_ws;
    auto alloc = [&](size_t bytes) {
        char* p = w;
        w += (bytes + 255) & ~(size_t)255;
        return p;
    };
    bf16_t* xb      = (bf16_t*)alloc((size_t)NTOK * D * 2);
    bf16_t* gut     = (bf16_t*)alloc((size_t)E * 2 * I * D * 2);   // [E][2I][D] interleaved
    bf16_t* dnt     = (bf16_t*)alloc((size_t)E * D * I * 2);       // [E][D][I]
    bf16_t* sh1t    = (bf16_t*)alloc((size_t)2 * I * D * 2);       // [2I][D] interleaved
    bf16_t* sdt     = (bf16_t*)alloc((size_t)D * I * 2);           // [D][I]
    bf16_t* inter   = (bf16_t*)alloc((size_t)NK * I * 2);
    bf16_t* inter_s = (bf16_t*)alloc((size_t)NTOK * I * 2);
    float*  tkw     = (float*)alloc((size_t)NK * 4);
    int*    tke     = (int*)alloc((size_t)NK * 4);
    int*    stok    = (int*)alloc((size_t)NK * 4);
    int*    sinv    = (int*)alloc((size_t)NK * 4);
    int*    counts  = (int*)alloc(E * 4);
    int*    offs    = (int*)alloc((E + 1) * 4);
    int*    curs    = (int*)alloc(E * 4);
    int4*   ttbl    = (int4*)alloc(MAX_TILES * 16);
    int*    ntl     = (int*)alloc(4);
    // outS[NK][D] bf16 (256MB) aliases gut (256MB): gut is dead after expert gemm1
    bf16_t* outS    = gut;

    if ((size_t)(w - (char*)d_ws) > ws_size) {
        k_sentinel<<<1, 64, 0, stream>>>(out);
        return;
    }

    k_zero_meta<<<1, 64, 0, stream>>>(counts, curs, ntl);
    k_convert_x<<<(NTOK * D / 8 + 255) / 256, 256, 0, stream>>>(x, xb, NTOK * D / 8);

    // weight reshapes
    k_transpose<1><<<dim3(2 * I / 32, D / 32, E), dim3(32, 8), 0, stream>>>(
        gu, gut, D, 2 * I, (size_t)D * 2 * I, (size_t)D * 2 * I);
    k_transpose<0><<<dim3(D / 32, I / 32, E), dim3(32, 8), 0, stream>>>(
        dn, dnt, I, D, (size_t)I * D, (size_t)I * D);
    k_transpose<2><<<dim3(I / 32, D / 32, 1), dim3(32, 8), 0, stream>>>(
        sg, sh1t, D, I, 0, 0);
    k_transpose<3><<<dim3(I / 32, D / 32, 1), dim3(32, 8), 0, stream>>>(
        su, sh1t, D, I, 0, 0);
    k_transpose<0><<<dim3(D / 32, I / 32, 1), dim3(32, 8), 0, stream>>>(
        sd, sdt, I, D, 0, 0);

    // routing
    k_router<<<NTOK, 256, 0, stream>>>(x, gw, eb, out_idx, out_scores, tkw, tke, counts);
    k_offsets<<<1, 64, 0, stream>>>(counts, offs, ttbl, ntl);
    k_scatter<<<NK / 256, 256, 0, stream>>>(tke, offs, curs, stok, sinv);

    constexpr size_t SMEM = 131072;
    // expert path (gemm1 must finish before outS overwrites gut)
    k_mm8<true, true, 0><<<dim3(8, MAX_TILES), 512, SMEM, stream>>>(
        xb, gut, D, (size_t)2 * I * D, stok, ttbl, ntl, inter, I);
    k_mm8<true, false, 1><<<dim3(8, MAX_TILES), 512, SMEM, stream>>>(
        inter, dnt, I, (size_t)D * I, stok, ttbl, ntl, outS, D);

    // shared path
    k_mm8<false, false, 0><<<dim3(8, NTOK / TM), 512, SMEM, stream>>>(
        xb, sh1t, D, 0, nullptr, nullptr, nullptr, inter_s, I);
    k_mm8<false, false, 2><<<dim3(8, NTOK / TM), 512, SMEM, stream>>>(
        inter_s, sdt, I, 0, nullptr, nullptr, nullptr, out, D);

    // combine
    k_finalize<<<NTOK, 256, 0, stream>>>(outS, sinv, tkw, out);
}